// Round 20
// baseline (295.281 us; speedup 1.0000x reference)
//
#include <hip/hip_runtime.h>

// AutoDecoderLayer on MI355X.
// Algebra: with X=embdding, Y=history,
//   G = X^T X ; scoresT_h = (Wq_h G Wk_h^T + rank-1 bias)/32 (= scores^T)
//   AT_h = colsoftmax(scoresT_h) ; c_h = AT_h bv_h
//   M = sum_h Wv_h^T A_h Wz_h^T ;  d = bz + (Wz c)
//   O = Y M + d ; LN1 = LN(O)+X ; FN = LN1 Wf^T + bf ; out = LN(FN)+LN1
// R18: symmetric Gram + separate colstat2 (269us).
// R19: (1) FULL-K Gram (72 symmetric tiles, K=4096) writing Gbf directly —
// eliminates split-K partials Gp (16MB) and the gram_red pass; GEMM blocks
// hide under the conversion stream. (2) MpT = Wz_h C_h^T (operand swap) so
// the head-sum is a plain 8-plane strided reduction (gram_red_k reused);
// mred_tr's LDS transpose deleted.

constexpr int EMB = 1024;
constexpr int SEQ = 4096;
constexpr int NH  = 8;

using f32x4  = __attribute__((ext_vector_type(4))) float;
using bf16x8 = __attribute__((ext_vector_type(8))) __bf16;
using us8    = __attribute__((ext_vector_type(8))) unsigned short;
using us4    = __attribute__((ext_vector_type(4))) unsigned short;

#define GLOAD_LDS16(g, l) __builtin_amdgcn_global_load_lds(                 \
    (const __attribute__((address_space(1))) void*)(g),                     \
    (__attribute__((address_space(3))) void*)(l), 16, 0, 0)

__device__ inline unsigned short f2bf(float x) {
  unsigned int u = __float_as_uint(x);
  u += 0x7FFFu + ((u >> 16) & 1u);   // round-to-nearest-even
  return (unsigned short)(u >> 16);
}
__device__ inline float bf2f(unsigned short h) {
  return __uint_as_float(((unsigned int)h) << 16);
}
__device__ inline f32x4 ntl4(const float* p) {
  return __builtin_nontemporal_load((const f32x4*)p);
}
__device__ inline us4 cvt4(f32x4 x) {
  us4 o; o[0] = f2bf(x[0]); o[1] = f2bf(x[1]); o[2] = f2bf(x[2]); o[3] = f2bf(x[3]);
  return o;
}

// ---------------------------------------------------------------- GEMM body
// C[m,n] = sum_k A[m*lda+k] * B[n*ldb+k], bf16 in, f32 acc.
// 64x128 tile, BK=64, 4 waves (2x2), single-buffered 24KB LDS, async
// global_load_lds staging. MODE 1: bf16 store. 2: bf16 store + transposed
// MIRROR store (symmetric Gram). 4: scoresT bf16 + col-softmax partials.
// 5: bf16 store + bias[n]. bx/by/z pre-decoded by caller.
template <int MODE>
__device__ __attribute__((always_inline)) void gemm_body(
    unsigned short* lds, int bx, int by, int z,
    const unsigned short* A, const unsigned short* B, void* Cout,
    int K, int lda, int ldb, int ldc,
    long long aZ, long long bZ, long long cZ,
    const float* e0, const float* e1, const float* e2, const float* e3,
    float* mpart, float* spart) {
  A += (size_t)z * aZ;
  B += (size_t)z * bZ;
  const int tid = threadIdx.x;
  const int lane = tid & 63, wid = tid >> 6;
  const int wm = wid >> 1, wn = wid & 1;     // 2x2 wave grid
  const int row0 = bx * 64, col0 = by * 128;

  unsigned short* As = lds;                  // [64][64]  8KB
  unsigned short* Bs = lds + 64 * 64;        // [128][64] 16KB

  f32x4 acc[2][4] = {};
  const int lrow = lane & 15, kg = lane >> 4;
  const int lr = lane >> 3;        // row within an 8-row chunk
  const int lc = (lane & 7) * 8;   // elem col within 64

  const int nt = K >> 6;
  for (int t = 0; t < nt; ++t) {
    const int k0 = t << 6;
#pragma unroll
    for (int c = 0; c < 2; ++c) {
      int chunk = wid * 2 + c;
      int r = chunk * 8 + lr;
      GLOAD_LDS16(A + (size_t)(row0 + r) * lda + k0 + lc, &As[chunk * 512]);
    }
#pragma unroll
    for (int c = 0; c < 4; ++c) {
      int chunk = wid * 4 + c;
      int r = chunk * 8 + lr;
      GLOAD_LDS16(B + (size_t)(col0 + r) * ldb + k0 + lc, &Bs[chunk * 512]);
    }
    __syncthreads();
#pragma unroll
    for (int ks = 0; ks < 2; ++ks) {
      bf16x8 a[2], b[4];
      int koff = ks * 32 + kg * 8;
#pragma unroll
      for (int i = 0; i < 2; ++i)
        a[i] = *(const bf16x8*)&As[(wm * 32 + i * 16 + lrow) * 64 + koff];
#pragma unroll
      for (int j = 0; j < 4; ++j)
        b[j] = *(const bf16x8*)&Bs[(wn * 64 + j * 16 + lrow) * 64 + koff];
#pragma unroll
      for (int i = 0; i < 2; ++i)
#pragma unroll
        for (int j = 0; j < 4; ++j)
          acc[i][j] = __builtin_amdgcn_mfma_f32_16x16x32_bf16(a[i], b[j], acc[i][j], 0, 0, 0);
    }
    __syncthreads();
  }

  const int rb = (lane >> 4) * 4, cc = lane & 15;
  unsigned short* Cs = lds;                // [64][128] 16KB
#pragma unroll
  for (int i = 0; i < 2; ++i) {
#pragma unroll
    for (int j = 0; j < 4; ++j) {
#pragma unroll
      for (int r = 0; r < 4; ++r) {
        float val = acc[i][j][r];
        int mm = wm * 32 + i * 16 + rb + r;
        int nn = wn * 64 + j * 16 + cc;
        if (MODE == 4) {
          int m = row0 + mm, n = col0 + nn;
          float bq = e0[z * EMB + m], uu = e1[z * EMB + n];
          float bk = e2[z * EMB + n], vv = e3[z * EMB + m];
          val = (val + bq * (uu + (float)SEQ * bk) + vv * bk) * (1.0f / 32.0f);
        } else if (MODE == 5) {
          val += e0[col0 + nn];
        }
        Cs[mm * 128 + nn] = f2bf(val);
      }
    }
  }
  __syncthreads();
  unsigned short* Cg = (unsigned short*)Cout + (size_t)z * cZ;
#pragma unroll
  for (int p = 0; p < 4; ++p) {
    int idx = p * 256 + tid;
    int row = idx >> 4, col = (idx & 15) * 8;
    *(us8*)(Cg + (size_t)(row0 + row) * ldc + col0 + col) =
        *(const us8*)&Cs[row * 128 + col];
  }
  if (MODE == 2) {
    // mirror store: G[col0+nn][row0+mm] = Cs[mm][nn] (identical values at
    // overlaps -> benign). 128 rows x 64 cols, us8 chunks (8 bf16).
#pragma unroll
    for (int p = 0; p < 4; ++p) {
      int idx = p * 256 + tid;               // 1024 chunks
      int rr = idx >> 3;                     // mirror row: nn in [0,128)
      int cg = (idx & 7) * 8;                // mirror col group: mm base
      us8 o;
#pragma unroll
      for (int e = 0; e < 8; ++e) o[e] = Cs[(cg + e) * 128 + rr];
      *(us8*)(Cg + (size_t)(col0 + rr) * ldc + row0 + cg) = o;
    }
  }
  if (MODE == 4) {
    // column softmax partials over this tile's 64 rows (2 threads/col),
    // computed from the SAME bf16 values at_cvec will read back.
    int colx = tid >> 1, half = tid & 1;
    float mx = -1e30f;
#pragma unroll 8
    for (int r = 0; r < 32; ++r)
      mx = fmaxf(mx, bf2f(Cs[(half * 32 + r) * 128 + colx]));
    mx = fmaxf(mx, __shfl_xor(mx, 1));
    float se = 0.f;
#pragma unroll 8
    for (int r = 0; r < 32; ++r)
      se += __expf(bf2f(Cs[(half * 32 + r) * 128 + colx]) - mx);
    se += __shfl_xor(se, 1);
    if (half == 0) {
      size_t soff = ((size_t)z * 16 + bx) * EMB + col0 + colx;
      mpart[soff] = mx;
      spart[soff] = se;
    }
  }
}

template <int MODE>
__global__ __launch_bounds__(256) void gemm_nt(const unsigned short* __restrict__ A,
                                               const unsigned short* __restrict__ B,
                                               void* __restrict__ Cout,
                                               int K, int lda, int ldb, int ldc,
                                               long long aZ, long long bZ, long long cZ,
                                               int nx, int ny,
                                               const float* __restrict__ e0,
                                               const float* __restrict__ e1,
                                               const float* __restrict__ e2,
                                               const float* __restrict__ e3,
                                               float* __restrict__ mpart,
                                               float* __restrict__ spart) {
  __shared__ __align__(16) unsigned short lds[(64 + 128) * 64];
  const int q = gridDim.x >> 3;                       // nwg % 8 == 0
  const int wg = (blockIdx.x & 7) * q + (blockIdx.x >> 3);
  const int bx = wg % nx, by = (wg / nx) % ny, z = wg / (nx * ny);
  gemm_body<MODE>(lds, bx, by, z, A, B, Cout, K, lda, ldb, ldc, aZ, bZ, cZ,
                  e0, e1, e2, e3, mpart, spart);
}

// ------------------- colsum_part + emb-transpose + Wv-transpose (one dispatch)
// [0,128): colsum partials; [128,1152): emb 64x64 tiles -> XT;
// [1152,3200): Wv 64x64 tiles -> WvT
__global__ __launch_bounds__(256) void colsum_xt_k(const float* __restrict__ emb,
                                                   const float* __restrict__ Wv,
                                                   float* __restrict__ part,
                                                   unsigned short* __restrict__ XT,
                                                   unsigned short* __restrict__ WvT) {
  __shared__ float tileT[64][65];
  const int b = blockIdx.x, tid = threadIdx.x;
  if (b < 128) {
    int e = (b & 3) * 256 + tid;
    int y = b >> 2;
    float s = 0.f;
    for (int r = y * 128; r < y * 128 + 128; ++r) s += emb[(size_t)r * EMB + e];
    part[y * EMB + e] = s;
    return;
  }
  const float* src; unsigned short* dst; int R, r0, c0;
  if (b < 1152) {
    int tb = b - 128;                      // emb [4096][1024] -> XT [1024][4096]
    src = emb; dst = XT; R = SEQ;
    r0 = (tb >> 4) * 64; c0 = (tb & 15) * 64;
  } else {
    int t2 = b - 1152, z = t2 >> 8, tt = t2 & 255;
    src = Wv + (size_t)z * EMB * EMB; dst = WvT + (size_t)z * EMB * EMB;
    R = EMB;
    r0 = (tt >> 4) * 64; c0 = (tt & 15) * 64;
  }
  int tx = tid & 15, ty = tid >> 4;        // 16 x 16 threads
#pragma unroll
  for (int p = 0; p < 4; ++p) {            // NT float4 loads, transposed scatter
    int ir = p * 16 + ty;
    f32x4 x = ntl4(src + (size_t)(r0 + ir) * EMB + c0 + tx * 4);
    tileT[tx * 4 + 0][ir] = x[0]; tileT[tx * 4 + 1][ir] = x[1];
    tileT[tx * 4 + 2][ir] = x[2]; tileT[tx * 4 + 3][ir] = x[3];
  }
  __syncthreads();
#pragma unroll
  for (int p = 0; p < 4; ++p) {            // contiguous LDS read, normal stores
    int orow = p * 16 + ty;
    f32x4 x;
    x[0] = tileT[orow][tx * 4 + 0]; x[1] = tileT[orow][tx * 4 + 1];
    x[2] = tileT[orow][tx * 4 + 2]; x[3] = tileT[orow][tx * 4 + 3];
    *(us4*)(dst + (size_t)(c0 + orow) * R + r0 + tx * 4) = cvt4(x);
  }
}

__global__ __launch_bounds__(256) void colsum_red_k(const float* __restrict__ part,
                                                    float* __restrict__ xbar) {
  int e = blockIdx.x * 256 + threadIdx.x;
  float s = 0.f;
  for (int y = 0; y < 32; ++y) s += part[y * EMB + e];
  xbar[e] = s;
}

// -------- FUSED: FULL-K symmetric Gram GEMM (blocks [0,72)) + conversions
// Gram: 72 tiles (bx>=2by), K=4096, mirror-stored, writes Gbf directly.
// 72 = 8 XCDs x 9 -> swizzle bijective. GEMM blocks first.
// [72,4168)    Wk/Wq: one row per wave -> bf16 + dot(xbar) -> u/v
// [4168,5832)  flat conversions, 8192 f32/block: hist | Wz | Wf
__global__ __launch_bounds__(256) void gram_cvt_k(
    const unsigned short* __restrict__ XT, unsigned short* __restrict__ Gbf,
    const float* __restrict__ Wk, const float* __restrict__ Wq,
    const float* __restrict__ hist, const float* __restrict__ Wz,
    const float* __restrict__ Wf, const float* __restrict__ xbar,
    unsigned short* __restrict__ Wkb, unsigned short* __restrict__ Wqb,
    unsigned short* __restrict__ Yb, unsigned short* __restrict__ Wzb,
    unsigned short* __restrict__ Wfb,
    float* __restrict__ u, float* __restrict__ v) {
  __shared__ __align__(16) unsigned short smem[(64 + 128) * 64];  // 24KB union
  const int tid = threadIdx.x;
  if (blockIdx.x < 72) {
    const int t = ((int)blockIdx.x & 7) * 9 + ((int)blockIdx.x >> 3);  // [0,72)
    // decode t -> (bx,by): starts[by] = 16by - by(by-1)
    int by = 0, st = 0;
#pragma unroll
    for (int b = 7; b >= 1; --b) {
      int sb = 16 * b - b * (b - 1);
      if (t >= sb && by == 0) { by = b; st = sb; }
    }
    int bx = 2 * by + (t - st);
    gemm_body<2>(smem, bx, by, 0, XT, XT, Gbf, SEQ, SEQ, SEQ, EMB,
                 0, 0, 0,
                 nullptr, nullptr, nullptr, nullptr, nullptr, nullptr);
    return;
  }
  int c = blockIdx.x - 72;
  if (c < 4096) {                        // cvt + xbar-dot, one row per wave
    int gw = c * 4 + (tid >> 6);
    int lane = tid & 63;
    const float* src = (gw < 8192) ? Wk : Wq;
    unsigned short* dst = (gw < 8192) ? Wkb : Wqb;
    float* dot = (gw < 8192) ? u : v;
    int row = gw & 8191;
    const float* sr = src + (size_t)row * EMB;
    const float4* xb4 = (const float4*)xbar;
    unsigned short* dr = dst + (size_t)row * EMB;
    float s = 0.f;
#pragma unroll
    for (int j = 0; j < 4; ++j) {
      int idx = j * 64 + lane;
      f32x4 x = ntl4(sr + idx * 4);
      float4 xb = xb4[idx];
      *(us4*)(dr + idx * 4) = cvt4(x);
      s += x[0] * xb.x + x[1] * xb.y + x[2] * xb.z + x[3] * xb.w;
    }
#pragma unroll
    for (int off = 32; off; off >>= 1) s += __shfl_down(s, off);
    if (lane == 0) dot[row] = s;
  } else {                               // flat conversions, 8192 f32/block
    size_t f0 = (size_t)(c - 4096) * 8192;
    const float* src; unsigned short* dst; size_t loc;
    if (f0 < 4194304ull) { src = hist; dst = Yb; loc = f0; }
    else if (f0 < 12582912ull) { src = Wz; dst = Wzb; loc = f0 - 4194304ull; }
    else { src = Wf; dst = Wfb; loc = f0 - 12582912ull; }
#pragma unroll
    for (int p = 0; p < 8; ++p) {
      int i = p * 256 + tid;
      f32x4 x = ntl4(src + loc + i * 4);
      *(us4*)(dst + loc + i * 4) = cvt4(x);
    }
  }
}

// ------- FUSED: MpT GEMM (blocks [0,1024)) + dvec.  MpT_h = Wz_h * C_h^T
// (A = Wzb rows, lda=8192, head offset aZ=EMB in k; B = Cbf planes).
__global__ __launch_bounds__(256) void mp_dvec_k(
    const unsigned short* __restrict__ Cbf, const unsigned short* __restrict__ Wzb,
    unsigned short* __restrict__ MpT,
    const float* __restrict__ bz, const float* __restrict__ cvec,
    float* __restrict__ d) {
  __shared__ __align__(16) unsigned short smem[(64 + 128) * 64];
  const int tid = threadIdx.x;
  if (blockIdx.x < 1024) {
    const int wg = ((int)blockIdx.x & 7) * 128 + ((int)blockIdx.x >> 3);
    const int bx = wg % 16, by = (wg / 16) % 8, z = wg / 128;
    gemm_body<1>(smem, bx, by, z, Wzb, Cbf, MpT, EMB, NH * EMB, EMB, EMB,
                 (long long)EMB, (long long)EMB * EMB, (long long)EMB * EMB,
                 nullptr, nullptr, nullptr, nullptr, nullptr, nullptr);
    return;
  }
  // dvec: d[g] = bz[g] + dot(Wzb[g,:], cvec)
  int g = blockIdx.x - 1024;
  float* sb = (float*)smem;
  const unsigned short* row = Wzb + (size_t)g * (NH * EMB);
  float s = 0.f;
#pragma unroll
  for (int p = 0; p < 4; ++p) {
    int i = p * 256 + tid;
    us8 w = ((const us8*)row)[i];
    float4 c0 = ((const float4*)cvec)[i * 2];
    float4 c1 = ((const float4*)cvec)[i * 2 + 1];
    s += bf2f(w[0]) * c0.x + bf2f(w[1]) * c0.y + bf2f(w[2]) * c0.z + bf2f(w[3]) * c0.w;
    s += bf2f(w[4]) * c1.x + bf2f(w[5]) * c1.y + bf2f(w[6]) * c1.z + bf2f(w[7]) * c1.w;
  }
  int lane = tid & 63, w = tid >> 6;
#pragma unroll
  for (int off = 32; off; off >>= 1) s += __shfl_down(s, off);
  if (lane == 0) sb[w] = s;
  __syncthreads();
  if (tid == 0) d[g] = bz[g] + sb[0] + sb[1] + sb[2] + sb[3];
}

// out[i] = bf16( sum_z in[z][i] ), 8 bf16 planes (used for MpT -> MT)
__global__ __launch_bounds__(256) void plane_red_k(const unsigned short* __restrict__ in,
                                                   unsigned short* __restrict__ out) {
  int i = blockIdx.x * 256 + threadIdx.x;  // ushort4 index
  float4 s = {0.f, 0.f, 0.f, 0.f};
#pragma unroll
  for (int z = 0; z < 8; ++z) {
    ushort4 v = ((const ushort4*)(in + (size_t)z * EMB * EMB))[i];
    s.x += bf2f(v.x); s.y += bf2f(v.y); s.z += bf2f(v.z); s.w += bf2f(v.w);
  }
  ushort4 o; o.x = f2bf(s.x); o.y = f2bf(s.y); o.z = f2bf(s.z); o.w = f2bf(s.w);
  ((ushort4*)out)[i] = o;
}

// ------------------------------------------- transposed-softmax pipeline
__global__ __launch_bounds__(256) void colstat2_k(const float* __restrict__ m_part,
                                                  const float* __restrict__ s_part,
                                                  float* __restrict__ mfin,
                                                  float* __restrict__ isfin) {
  int i = blockIdx.x * 256 + threadIdx.x;     // (h,col) flat, grid = 32
  int h = i >> 10, col = i & 1023;
  float M = -1e30f, S = 0.f;
#pragma unroll
  for (int c = 0; c < 16; ++c) {
    float m = m_part[((size_t)h * 16 + c) * EMB + col];
    float s = s_part[((size_t)h * 16 + c) * EMB + col];
    float nm = fmaxf(M, m);
    S = S * __expf(M - nm) + s * __expf(m - nm);
    M = nm;
  }
  mfin[i] = M;
  isfin[i] = 1.0f / S;
}

__global__ __launch_bounds__(256) void at_cvec_k(const unsigned short* __restrict__ ScT,
                                                 const float* __restrict__ mfin,
                                                 const float* __restrict__ isfin,
                                                 const float* __restrict__ bv,
                                                 unsigned short* __restrict__ AT,
                                                 float* __restrict__ cbuf) {
  __shared__ float sb[4];
  int f = blockIdx.x, h = blockIdx.y, tid = threadIdx.x;
  size_t rowoff = ((size_t)h * EMB + f) * EMB;
  ushort4 xr = ((const ushort4*)(ScT + rowoff))[tid];
  float4 m  = ((const float4*)(mfin + (size_t)h * EMB))[tid];
  float4 is = ((const float4*)(isfin + (size_t)h * EMB))[tid];
  float4 b  = ((const float4*)(bv + (size_t)h * EMB))[tid];
  float a0 = __expf(bf2f(xr.x) - m.x) * is.x;
  float a1 = __expf(bf2f(xr.y) - m.y) * is.y;
  float a2 = __expf(bf2f(xr.z) - m.z) * is.z;
  float a3 = __expf(bf2f(xr.w) - m.w) * is.w;
  ushort4 o; o.x = f2bf(a0); o.y = f2bf(a1); o.z = f2bf(a2); o.w = f2bf(a3);
  ((ushort4*)(AT + rowoff))[tid] = o;
  float s = a0 * b.x + a1 * b.y + a2 * b.z + a3 * b.w;
  int lane = tid & 63, w = tid >> 6;
#pragma unroll
  for (int off = 32; off; off >>= 1) s += __shfl_down(s, off);
  if (lane == 0) sb[w] = s;
  __syncthreads();
  if (tid == 0) cbuf[h * EMB + f] = sb[0] + sb[1] + sb[2] + sb[3];
}

// ---------------------------------------------------------------- LN
// Xin is bf16 (GEMM MODE-5 output); stats in f32; residual f32.
__global__ __launch_bounds__(256) void layernorm_k(const unsigned short* __restrict__ Xin,
                                                   const float* __restrict__ resid,
                                                   const float* __restrict__ gw,
                                                   const float* __restrict__ bw,
                                                   float* __restrict__ outf,
                                                   unsigned short* __restrict__ outb) {
  __shared__ float sb[16];
  int row = blockIdx.x, tid = threadIdx.x;
  ushort4 xr = ((const ushort4*)(Xin + (size_t)row * EMB))[tid];
  float v0 = bf2f(xr.x), v1 = bf2f(xr.y), v2 = bf2f(xr.z), v3 = bf2f(xr.w);
  float s = v0 + v1 + v2 + v3;
  float q = v0 * v0 + v1 * v1 + v2 * v2 + v3 * v3;
  int lane = tid & 63, w = tid >> 6;
#pragma unroll
  for (int off = 32; off; off >>= 1) { s += __shfl_down(s, off); q += __shfl_down(q, off); }
  if (lane == 0) { sb[w] = s; sb[8 + w] = q; }
  __syncthreads();
  float mu  = (sb[0] + sb[1] + sb[2] + sb[3]) * (1.0f / EMB);
  float var = (sb[8] + sb[9] + sb[10] + sb[11]) * (1.0f / EMB) - mu * mu;
  float rs = rsqrtf(var + 1e-5f);
  float4 rv = ((const float4*)(resid + (size_t)row * EMB))[tid];
  float4 gv = ((const float4*)gw)[tid];
  float4 bv = ((const float4*)bw)[tid];
  float o0 = (v0 - mu) * rs * gv.x + bv.x + rv.x;
  float o1 = (v1 - mu) * rs * gv.y + bv.y + rv.y;
  float o2 = (v2 - mu) * rs * gv.z + bv.z + rv.z;
  float o3 = (v3 - mu) * rs * gv.w + bv.w + rv.w;
  float4 ov; ov.x = o0; ov.y = o1; ov.z = o2; ov.w = o3;
  ((float4*)(outf + (size_t)row * EMB))[tid] = ov;
  if (outb) {
    ushort4 ob; ob.x = f2bf(o0); ob.y = f2bf(o1); ob.z = f2bf(o2); ob.w = f2bf(o3);
    ((ushort4*)(outb + (size_t)row * EMB))[tid] = ob;
  }
}

// ---------------------------------------------------------------- launch
extern "C" void kernel_launch(void* const* d_in, const int* in_sizes, int n_in,
                              void* d_out, int out_size, void* d_ws, size_t ws_size,
                              hipStream_t stream) {
  const float* history = (const float*)d_in[0];
  const float* emb     = (const float*)d_in[1];
  const float* Wq_w = (const float*)d_in[2];
  const float* Wq_b = (const float*)d_in[3];
  const float* Wk_w = (const float*)d_in[4];
  const float* Wk_b = (const float*)d_in[5];
  const float* Wv_w = (const float*)d_in[6];
  const float* Wv_b = (const float*)d_in[7];
  const float* Wz_w = (const float*)d_in[8];
  const float* Wz_b = (const float*)d_in[9];
  const float* ln1_g = (const float*)d_in[10];
  const float* ln1_b = (const float*)d_in[11];
  const float* Wf_w = (const float*)d_in[12];
  const float* Wf_b = (const float*)d_in[13];
  const float* ln2_g = (const float*)d_in[14];
  const float* ln2_b = (const float*)d_in[15];

  char* ws = (char*)d_ws;
  const size_t MB = 1024ull * 1024ull;
  unsigned short* XT  = (unsigned short*)(ws + 0);        // [E][S] bf16, 8MB ; later LN1bf
  unsigned short* Ybf = (unsigned short*)(ws + 8 * MB);   // [S][E] bf16, 8MB
  unsigned short* Wkb = (unsigned short*)(ws + 16 * MB);  // [H][E][E] bf16, 16MB
  unsigned short* Wqb = (unsigned short*)(ws + 32 * MB);
  unsigned short* WvT = (unsigned short*)(ws + 48 * MB);  // [H][E'][E] transposed
  unsigned short* Wzb = (unsigned short*)(ws + 64 * MB);  // [E][H*E]
  unsigned short* Wfb = (unsigned short*)(ws + 80 * MB);  // [E][E], 2MB
  unsigned short* Gbf = (unsigned short*)(ws + 82 * MB);  // [E][E] bf16 (symmetric), 2MB
  float* xpart = (float*)(ws + 84 * MB);                  // 128 KB
  float* xbar  = (float*)(ws + 84 * MB + 160 * 1024);     // 4 KB
  float* ubuf  = (float*)(ws + 84 * MB + 192 * 1024);     // [H][E] 32 KB
  float* vbuf  = (float*)(ws + 84 * MB + 256 * 1024);
  float* cbuf  = (float*)(ws + 84 * MB + 320 * 1024);     // [H][E]
  float* dbuf  = (float*)(ws + 84 * MB + 384 * 1024);     // [E]
  unsigned short* Tbf = (unsigned short*)(ws + 85 * MB);  // 16MB; later Cbf, later FNbf
  float* Sc  = (float*)(ws + 101 * MB);                   // 32MB region: ScT/MpT (bf16)
  char*  St  = ws + 133 * MB;                             // stats; later Obf
  unsigned short* ATb = (unsigned short*)(ws + 149 * MB); // 16MB; later LN1 f32
  unsigned short* MTb = (unsigned short*)(ws + 165 * MB); // 2MB
  float* m_part = (float*)(St);                  // 512 KB [H][16][E]
  float* s_part = (float*)(St + 512 * 1024);     // 512 KB
  float* mfin   = (float*)(St + 1024 * 1024);    // 32 KB [H][E]
  float* isfin  = (float*)(St + 1056 * 1024);    // 32 KB
  // aliases (lifetimes verified non-overlapping)
  unsigned short* ScT = (unsigned short*)Sc;  // [H][E][E] bf16 scoresT
  unsigned short* Cbf = Tbf;
  unsigned short* MpT = (unsigned short*)Sc;  // [H][E][E] bf16, after ScT consumed
  unsigned short* Obf = (unsigned short*)St;  // [S][E] bf16 (after stats consumed)
  float* LN1  = (float*)ATb;
  unsigned short* LN1b = XT;
  unsigned short* FNbf = Tbf;                 // [S][E] bf16 (after Cbf consumed)
  const long long EE = (long long)EMB * EMB;

  // --- colsum partials + emb/Wv transposes (one dispatch), then xbar
  colsum_xt_k<<<dim3(3200), 256, 0, stream>>>(emb, Wv_w, xpart, XT, WvT);
  colsum_red_k<<<dim3(4), 256, 0, stream>>>(xpart, xbar);

  // --- FUSED: full-K symmetric Gram (writes Gbf directly) + conversions
  gram_cvt_k<<<dim3(5832), 256, 0, stream>>>(XT, Gbf,
                                             Wk_w, Wq_w, history, Wz_w, Wf_w,
                                             xbar,
                                             Wkb, Wqb, Ybf, Wzb, Wfb,
                                             ubuf, vbuf);
  // --- T2_h = Wq_h * G  (G symmetric; NT B-operand)
  gemm_nt<1><<<dim3(1024), 256, 0, stream>>>(Wqb, Gbf, Tbf, EMB, EMB, EMB, EMB,
                                             EE, 0, EE, 16, 8,
                                             nullptr, nullptr, nullptr, nullptr,
                                             nullptr, nullptr);
  // --- scoresT_h = (T2_h * Wk_h^T + rank-1)/32 -> bf16 + col-stat partials
  gemm_nt<4><<<dim3(1024), 256, 0, stream>>>(Tbf, Wkb, ScT, EMB, EMB, EMB, EMB,
                                             EE, EE, EE, 16, 8,
                                             Wq_b, ubuf, Wk_b, vbuf,
                                             m_part, s_part);
  // --- merge column softmax stats (32 blocks, done once)
  colstat2_k<<<dim3(32), 256, 0, stream>>>(m_part, s_part, mfin, isfin);
  // --- AT = exp(scoresT - m)*is (bf16) fused with cvec dot
  at_cvec_k<<<dim3(EMB, NH), 256, 0, stream>>>(ScT, mfin, isfin, Wv_b, ATb, cbuf);
  // --- C_h = WvT_h * AT_h^T  == Wv_h^T A_h
  gemm_nt<1><<<dim3(1024), 256, 0, stream>>>(WvT, ATb, Cbf, EMB, EMB, EMB, EMB,
                                             EE, EE, EE, 16, 8,
                                             nullptr, nullptr, nullptr, nullptr,
                                             nullptr, nullptr);
  // --- FUSED: MpT_h = Wz_h * C_h^T + dvec
  mp_dvec_k<<<dim3(2048), 256, 0, stream>>>(Cbf, Wzb, MpT, Wz_b, cbuf, dbuf);
  // --- MT = sum_h MpT_h (plain 8-plane reduction, no transpose)
  plane_red_k<<<dim3(EMB * EMB / 4 / 256), 256, 0, stream>>>(MpT, MTb);
  // --- O = Y * M + d  (bf16 out; stats region consumed already)
  gemm_nt<5><<<dim3(512), 256, 0, stream>>>(Ybf, MTb, Obf, EMB, EMB, EMB, EMB,
                                            0, 0, 0, 64, 8,
                                            dbuf, nullptr, nullptr, nullptr,
                                            nullptr, nullptr);
  // --- LN1 = LN(O)+emb (f32 + bf16 copies)
  layernorm_k<<<dim3(SEQ), 256, 0, stream>>>(Obf, emb, ln1_g, ln1_b, LN1, LN1b);
  // --- FN = LN1 * Wf^T + bf  (bf16 out, overwrites Cbf region)
  gemm_nt<5><<<dim3(512), 256, 0, stream>>>(LN1b, Wfb, FNbf, EMB, EMB, EMB, EMB,
                                            0, 0, 0, 64, 8,
                                            Wf_b, nullptr, nullptr, nullptr,
                                            nullptr, nullptr);
  // --- out = LN(FN)+LN1
  layernorm_k<<<dim3(SEQ), 256, 0, stream>>>(FNbf, LN1, ln2_g, ln2_b, (float*)d_out, nullptr);
}

// Round 21
// 266.870 us; speedup vs baseline: 1.1065x; 1.1065x over previous
//
#include <hip/hip_runtime.h>

// AutoDecoderLayer on MI355X.
// Algebra: with X=embdding, Y=history,
//   G = X^T X ; scoresT_h = (Wq_h G Wk_h^T + rank-1 bias)/32 (= scores^T)
//   AT_h = colsoftmax(scoresT_h) ; c_h = AT_h bv_h
//   M = sum_h Wv_h^T A_h Wz_h^T ;  d = bz + (Wz c)
//   O = Y M + d ; LN1 = LN(O)+X ; FN = LN1 Wf^T + bf ; out = LN(FN)+LN1
// R19 full-K Gram REVERTED: 72 blocks x K=4096 left a ~45us latency-bound
// serial tail after the conversion stream drained (1 block / 3.5 CUs).
// Split-K z=8 restored (576 symmetric tiles, short wide tail).
// KEPT from R19: MpT = Wz_h C_h^T operand swap + plane_red head-sum
// (no LDS transpose); plane_red_k reused for Gp->Gbf.

constexpr int EMB = 1024;
constexpr int SEQ = 4096;
constexpr int NH  = 8;

using f32x4  = __attribute__((ext_vector_type(4))) float;
using bf16x8 = __attribute__((ext_vector_type(8))) __bf16;
using us8    = __attribute__((ext_vector_type(8))) unsigned short;
using us4    = __attribute__((ext_vector_type(4))) unsigned short;

#define GLOAD_LDS16(g, l) __builtin_amdgcn_global_load_lds(                 \
    (const __attribute__((address_space(1))) void*)(g),                     \
    (__attribute__((address_space(3))) void*)(l), 16, 0, 0)

__device__ inline unsigned short f2bf(float x) {
  unsigned int u = __float_as_uint(x);
  u += 0x7FFFu + ((u >> 16) & 1u);   // round-to-nearest-even
  return (unsigned short)(u >> 16);
}
__device__ inline float bf2f(unsigned short h) {
  return __uint_as_float(((unsigned int)h) << 16);
}
__device__ inline f32x4 ntl4(const float* p) {
  return __builtin_nontemporal_load((const f32x4*)p);
}
__device__ inline us4 cvt4(f32x4 x) {
  us4 o; o[0] = f2bf(x[0]); o[1] = f2bf(x[1]); o[2] = f2bf(x[2]); o[3] = f2bf(x[3]);
  return o;
}

// ---------------------------------------------------------------- GEMM body
// C[m,n] = sum_k A[m*lda+k] * B[n*ldb+k], bf16 in, f32 acc.
// 64x128 tile, BK=64, 4 waves (2x2), single-buffered 24KB LDS, async
// global_load_lds staging. MODE 1: bf16 store. 2: bf16 store + transposed
// MIRROR store (symmetric Gram). 4: scoresT bf16 + col-softmax partials.
// 5: bf16 store + bias[n]. bx/by/z pre-decoded by caller.
template <int MODE>
__device__ __attribute__((always_inline)) void gemm_body(
    unsigned short* lds, int bx, int by, int z,
    const unsigned short* A, const unsigned short* B, void* Cout,
    int K, int lda, int ldb, int ldc,
    long long aZ, long long bZ, long long cZ,
    const float* e0, const float* e1, const float* e2, const float* e3,
    float* mpart, float* spart) {
  A += (size_t)z * aZ;
  B += (size_t)z * bZ;
  const int tid = threadIdx.x;
  const int lane = tid & 63, wid = tid >> 6;
  const int wm = wid >> 1, wn = wid & 1;     // 2x2 wave grid
  const int row0 = bx * 64, col0 = by * 128;

  unsigned short* As = lds;                  // [64][64]  8KB
  unsigned short* Bs = lds + 64 * 64;        // [128][64] 16KB

  f32x4 acc[2][4] = {};
  const int lrow = lane & 15, kg = lane >> 4;
  const int lr = lane >> 3;        // row within an 8-row chunk
  const int lc = (lane & 7) * 8;   // elem col within 64

  const int nt = K >> 6;
  for (int t = 0; t < nt; ++t) {
    const int k0 = t << 6;
#pragma unroll
    for (int c = 0; c < 2; ++c) {
      int chunk = wid * 2 + c;
      int r = chunk * 8 + lr;
      GLOAD_LDS16(A + (size_t)(row0 + r) * lda + k0 + lc, &As[chunk * 512]);
    }
#pragma unroll
    for (int c = 0; c < 4; ++c) {
      int chunk = wid * 4 + c;
      int r = chunk * 8 + lr;
      GLOAD_LDS16(B + (size_t)(col0 + r) * ldb + k0 + lc, &Bs[chunk * 512]);
    }
    __syncthreads();
#pragma unroll
    for (int ks = 0; ks < 2; ++ks) {
      bf16x8 a[2], b[4];
      int koff = ks * 32 + kg * 8;
#pragma unroll
      for (int i = 0; i < 2; ++i)
        a[i] = *(const bf16x8*)&As[(wm * 32 + i * 16 + lrow) * 64 + koff];
#pragma unroll
      for (int j = 0; j < 4; ++j)
        b[j] = *(const bf16x8*)&Bs[(wn * 64 + j * 16 + lrow) * 64 + koff];
#pragma unroll
      for (int i = 0; i < 2; ++i)
#pragma unroll
        for (int j = 0; j < 4; ++j)
          acc[i][j] = __builtin_amdgcn_mfma_f32_16x16x32_bf16(a[i], b[j], acc[i][j], 0, 0, 0);
    }
    __syncthreads();
  }

  const int rb = (lane >> 4) * 4, cc = lane & 15;
  unsigned short* Cs = lds;                // [64][128] 16KB
#pragma unroll
  for (int i = 0; i < 2; ++i) {
#pragma unroll
    for (int j = 0; j < 4; ++j) {
#pragma unroll
      for (int r = 0; r < 4; ++r) {
        float val = acc[i][j][r];
        int mm = wm * 32 + i * 16 + rb + r;
        int nn = wn * 64 + j * 16 + cc;
        if (MODE == 4) {
          int m = row0 + mm, n = col0 + nn;
          float bq = e0[z * EMB + m], uu = e1[z * EMB + n];
          float bk = e2[z * EMB + n], vv = e3[z * EMB + m];
          val = (val + bq * (uu + (float)SEQ * bk) + vv * bk) * (1.0f / 32.0f);
        } else if (MODE == 5) {
          val += e0[col0 + nn];
        }
        Cs[mm * 128 + nn] = f2bf(val);
      }
    }
  }
  __syncthreads();
  unsigned short* Cg = (unsigned short*)Cout + (size_t)z * cZ;
#pragma unroll
  for (int p = 0; p < 4; ++p) {
    int idx = p * 256 + tid;
    int row = idx >> 4, col = (idx & 15) * 8;
    *(us8*)(Cg + (size_t)(row0 + row) * ldc + col0 + col) =
        *(const us8*)&Cs[row * 128 + col];
  }
  if (MODE == 2) {
    // mirror store: G[col0+nn][row0+mm] = Cs[mm][nn] (identical values at
    // overlaps -> benign). 128 rows x 64 cols, us8 chunks (8 bf16).
#pragma unroll
    for (int p = 0; p < 4; ++p) {
      int idx = p * 256 + tid;               // 1024 chunks
      int rr = idx >> 3;                     // mirror row: nn in [0,128)
      int cg = (idx & 7) * 8;                // mirror col group: mm base
      us8 o;
#pragma unroll
      for (int e = 0; e < 8; ++e) o[e] = Cs[(cg + e) * 128 + rr];
      *(us8*)(Cg + (size_t)(col0 + rr) * ldc + row0 + cg) = o;
    }
  }
  if (MODE == 4) {
    // column softmax partials over this tile's 64 rows (2 threads/col),
    // computed from the SAME bf16 values at_cvec will read back.
    int colx = tid >> 1, half = tid & 1;
    float mx = -1e30f;
#pragma unroll 8
    for (int r = 0; r < 32; ++r)
      mx = fmaxf(mx, bf2f(Cs[(half * 32 + r) * 128 + colx]));
    mx = fmaxf(mx, __shfl_xor(mx, 1));
    float se = 0.f;
#pragma unroll 8
    for (int r = 0; r < 32; ++r)
      se += __expf(bf2f(Cs[(half * 32 + r) * 128 + colx]) - mx);
    se += __shfl_xor(se, 1);
    if (half == 0) {
      size_t soff = ((size_t)z * 16 + bx) * EMB + col0 + colx;
      mpart[soff] = mx;
      spart[soff] = se;
    }
  }
}

template <int MODE>
__global__ __launch_bounds__(256) void gemm_nt(const unsigned short* __restrict__ A,
                                               const unsigned short* __restrict__ B,
                                               void* __restrict__ Cout,
                                               int K, int lda, int ldb, int ldc,
                                               long long aZ, long long bZ, long long cZ,
                                               int nx, int ny,
                                               const float* __restrict__ e0,
                                               const float* __restrict__ e1,
                                               const float* __restrict__ e2,
                                               const float* __restrict__ e3,
                                               float* __restrict__ mpart,
                                               float* __restrict__ spart) {
  __shared__ __align__(16) unsigned short lds[(64 + 128) * 64];
  const int q = gridDim.x >> 3;                       // nwg % 8 == 0
  const int wg = (blockIdx.x & 7) * q + (blockIdx.x >> 3);
  const int bx = wg % nx, by = (wg / nx) % ny, z = wg / (nx * ny);
  gemm_body<MODE>(lds, bx, by, z, A, B, Cout, K, lda, ldb, ldc, aZ, bZ, cZ,
                  e0, e1, e2, e3, mpart, spart);
}

// ------------------- colsum_part + emb-transpose + Wv-transpose (one dispatch)
// [0,128): colsum partials; [128,1152): emb 64x64 tiles -> XT;
// [1152,3200): Wv 64x64 tiles -> WvT
__global__ __launch_bounds__(256) void colsum_xt_k(const float* __restrict__ emb,
                                                   const float* __restrict__ Wv,
                                                   float* __restrict__ part,
                                                   unsigned short* __restrict__ XT,
                                                   unsigned short* __restrict__ WvT) {
  __shared__ float tileT[64][65];
  const int b = blockIdx.x, tid = threadIdx.x;
  if (b < 128) {
    int e = (b & 3) * 256 + tid;
    int y = b >> 2;
    float s = 0.f;
    for (int r = y * 128; r < y * 128 + 128; ++r) s += emb[(size_t)r * EMB + e];
    part[y * EMB + e] = s;
    return;
  }
  const float* src; unsigned short* dst; int R, r0, c0;
  if (b < 1152) {
    int tb = b - 128;                      // emb [4096][1024] -> XT [1024][4096]
    src = emb; dst = XT; R = SEQ;
    r0 = (tb >> 4) * 64; c0 = (tb & 15) * 64;
  } else {
    int t2 = b - 1152, z = t2 >> 8, tt = t2 & 255;
    src = Wv + (size_t)z * EMB * EMB; dst = WvT + (size_t)z * EMB * EMB;
    R = EMB;
    r0 = (tt >> 4) * 64; c0 = (tt & 15) * 64;
  }
  int tx = tid & 15, ty = tid >> 4;        // 16 x 16 threads
#pragma unroll
  for (int p = 0; p < 4; ++p) {            // NT float4 loads, transposed scatter
    int ir = p * 16 + ty;
    f32x4 x = ntl4(src + (size_t)(r0 + ir) * EMB + c0 + tx * 4);
    tileT[tx * 4 + 0][ir] = x[0]; tileT[tx * 4 + 1][ir] = x[1];
    tileT[tx * 4 + 2][ir] = x[2]; tileT[tx * 4 + 3][ir] = x[3];
  }
  __syncthreads();
#pragma unroll
  for (int p = 0; p < 4; ++p) {            // contiguous LDS read, normal stores
    int orow = p * 16 + ty;
    f32x4 x;
    x[0] = tileT[orow][tx * 4 + 0]; x[1] = tileT[orow][tx * 4 + 1];
    x[2] = tileT[orow][tx * 4 + 2]; x[3] = tileT[orow][tx * 4 + 3];
    *(us4*)(dst + (size_t)(c0 + orow) * R + r0 + tx * 4) = cvt4(x);
  }
}

__global__ __launch_bounds__(256) void colsum_red_k(const float* __restrict__ part,
                                                    float* __restrict__ xbar) {
  int e = blockIdx.x * 256 + threadIdx.x;
  float s = 0.f;
  for (int y = 0; y < 32; ++y) s += part[y * EMB + e];
  xbar[e] = s;
}

// -------- FUSED: split-K symmetric Gram GEMM (blocks [0,576)) + conversions
// Gram: 72 tiles (bx>=2by) x 8 z, K=512 each, mirror-stored into Gp.
// GEMM blocks first so the (bx&7) swizzle aligns with round-robin XCDs.
// [576,4672)   Wk/Wq: one row per wave -> bf16 + dot(xbar) -> u/v
// [4672,6336)  flat conversions, 8192 f32/block: hist | Wz | Wf
__global__ __launch_bounds__(256) void gram_cvt_k(
    const unsigned short* __restrict__ XT, unsigned short* __restrict__ Gp,
    const float* __restrict__ Wk, const float* __restrict__ Wq,
    const float* __restrict__ hist, const float* __restrict__ Wz,
    const float* __restrict__ Wf, const float* __restrict__ xbar,
    unsigned short* __restrict__ Wkb, unsigned short* __restrict__ Wqb,
    unsigned short* __restrict__ Yb, unsigned short* __restrict__ Wzb,
    unsigned short* __restrict__ Wfb,
    float* __restrict__ u, float* __restrict__ v) {
  __shared__ __align__(16) unsigned short smem[(64 + 128) * 64];  // 24KB union
  const int tid = threadIdx.x;
  if (blockIdx.x < 576) {
    const int wg = ((int)blockIdx.x & 7) * 72 + ((int)blockIdx.x >> 3);
    const int t = wg % 72, z = wg / 72;
    // decode t -> (bx,by): starts[by] = 16by - by(by-1)
    int by = 0, st = 0;
#pragma unroll
    for (int b = 7; b >= 1; --b) {
      int sb = 16 * b - b * (b - 1);
      if (t >= sb && by == 0) { by = b; st = sb; }
    }
    int bx = 2 * by + (t - st);
    gemm_body<2>(smem, bx, by, z, XT, XT, Gp, 512, SEQ, SEQ, EMB,
                 512, 512, (long long)EMB * EMB,
                 nullptr, nullptr, nullptr, nullptr, nullptr, nullptr);
    return;
  }
  int c = blockIdx.x - 576;
  if (c < 4096) {                        // cvt + xbar-dot, one row per wave
    int gw = c * 4 + (tid >> 6);
    int lane = tid & 63;
    const float* src = (gw < 8192) ? Wk : Wq;
    unsigned short* dst = (gw < 8192) ? Wkb : Wqb;
    float* dot = (gw < 8192) ? u : v;
    int row = gw & 8191;
    const float* sr = src + (size_t)row * EMB;
    const float4* xb4 = (const float4*)xbar;
    unsigned short* dr = dst + (size_t)row * EMB;
    float s = 0.f;
#pragma unroll
    for (int j = 0; j < 4; ++j) {
      int idx = j * 64 + lane;
      f32x4 x = ntl4(sr + idx * 4);
      float4 xb = xb4[idx];
      *(us4*)(dr + idx * 4) = cvt4(x);
      s += x[0] * xb.x + x[1] * xb.y + x[2] * xb.z + x[3] * xb.w;
    }
#pragma unroll
    for (int off = 32; off; off >>= 1) s += __shfl_down(s, off);
    if (lane == 0) dot[row] = s;
  } else {                               // flat conversions, 8192 f32/block
    size_t f0 = (size_t)(c - 4096) * 8192;
    const float* src; unsigned short* dst; size_t loc;
    if (f0 < 4194304ull) { src = hist; dst = Yb; loc = f0; }
    else if (f0 < 12582912ull) { src = Wz; dst = Wzb; loc = f0 - 4194304ull; }
    else { src = Wf; dst = Wfb; loc = f0 - 12582912ull; }
#pragma unroll
    for (int p = 0; p < 8; ++p) {
      int i = p * 256 + tid;
      f32x4 x = ntl4(src + loc + i * 4);
      *(us4*)(dst + loc + i * 4) = cvt4(x);
    }
  }
}

// ------- FUSED: MpT GEMM (blocks [0,1024)) + dvec.  MpT_h = Wz_h * C_h^T
// (A = Wzb rows, lda=8192, head offset aZ=EMB in k; B = Cbf planes).
__global__ __launch_bounds__(256) void mp_dvec_k(
    const unsigned short* __restrict__ Cbf, const unsigned short* __restrict__ Wzb,
    unsigned short* __restrict__ MpT,
    const float* __restrict__ bz, const float* __restrict__ cvec,
    float* __restrict__ d) {
  __shared__ __align__(16) unsigned short smem[(64 + 128) * 64];
  const int tid = threadIdx.x;
  if (blockIdx.x < 1024) {
    const int wg = ((int)blockIdx.x & 7) * 128 + ((int)blockIdx.x >> 3);
    const int bx = wg % 16, by = (wg / 16) % 8, z = wg / 128;
    gemm_body<1>(smem, bx, by, z, Wzb, Cbf, MpT, EMB, NH * EMB, EMB, EMB,
                 (long long)EMB, (long long)EMB * EMB, (long long)EMB * EMB,
                 nullptr, nullptr, nullptr, nullptr, nullptr, nullptr);
    return;
  }
  // dvec: d[g] = bz[g] + dot(Wzb[g,:], cvec)
  int g = blockIdx.x - 1024;
  float* sb = (float*)smem;
  const unsigned short* row = Wzb + (size_t)g * (NH * EMB);
  float s = 0.f;
#pragma unroll
  for (int p = 0; p < 4; ++p) {
    int i = p * 256 + tid;
    us8 w = ((const us8*)row)[i];
    float4 c0 = ((const float4*)cvec)[i * 2];
    float4 c1 = ((const float4*)cvec)[i * 2 + 1];
    s += bf2f(w[0]) * c0.x + bf2f(w[1]) * c0.y + bf2f(w[2]) * c0.z + bf2f(w[3]) * c0.w;
    s += bf2f(w[4]) * c1.x + bf2f(w[5]) * c1.y + bf2f(w[6]) * c1.z + bf2f(w[7]) * c1.w;
  }
  int lane = tid & 63, w = tid >> 6;
#pragma unroll
  for (int off = 32; off; off >>= 1) s += __shfl_down(s, off);
  if (lane == 0) sb[w] = s;
  __syncthreads();
  if (tid == 0) d[g] = bz[g] + sb[0] + sb[1] + sb[2] + sb[3];
}

// out[i] = bf16( sum_z in[z][i] ), 8 bf16 planes (Gp->Gbf, MpT->MT)
__global__ __launch_bounds__(256) void plane_red_k(const unsigned short* __restrict__ in,
                                                   unsigned short* __restrict__ out) {
  int i = blockIdx.x * 256 + threadIdx.x;  // ushort4 index
  float4 s = {0.f, 0.f, 0.f, 0.f};
#pragma unroll
  for (int z = 0; z < 8; ++z) {
    ushort4 v = ((const ushort4*)(in + (size_t)z * EMB * EMB))[i];
    s.x += bf2f(v.x); s.y += bf2f(v.y); s.z += bf2f(v.z); s.w += bf2f(v.w);
  }
  ushort4 o; o.x = f2bf(s.x); o.y = f2bf(s.y); o.z = f2bf(s.z); o.w = f2bf(s.w);
  ((ushort4*)out)[i] = o;
}

// ------------------------------------------- transposed-softmax pipeline
__global__ __launch_bounds__(256) void colstat2_k(const float* __restrict__ m_part,
                                                  const float* __restrict__ s_part,
                                                  float* __restrict__ mfin,
                                                  float* __restrict__ isfin) {
  int i = blockIdx.x * 256 + threadIdx.x;     // (h,col) flat, grid = 32
  int h = i >> 10, col = i & 1023;
  float M = -1e30f, S = 0.f;
#pragma unroll
  for (int c = 0; c < 16; ++c) {
    float m = m_part[((size_t)h * 16 + c) * EMB + col];
    float s = s_part[((size_t)h * 16 + c) * EMB + col];
    float nm = fmaxf(M, m);
    S = S * __expf(M - nm) + s * __expf(m - nm);
    M = nm;
  }
  mfin[i] = M;
  isfin[i] = 1.0f / S;
}

__global__ __launch_bounds__(256) void at_cvec_k(const unsigned short* __restrict__ ScT,
                                                 const float* __restrict__ mfin,
                                                 const float* __restrict__ isfin,
                                                 const float* __restrict__ bv,
                                                 unsigned short* __restrict__ AT,
                                                 float* __restrict__ cbuf) {
  __shared__ float sb[4];
  int f = blockIdx.x, h = blockIdx.y, tid = threadIdx.x;
  size_t rowoff = ((size_t)h * EMB + f) * EMB;
  ushort4 xr = ((const ushort4*)(ScT + rowoff))[tid];
  float4 m  = ((const float4*)(mfin + (size_t)h * EMB))[tid];
  float4 is = ((const float4*)(isfin + (size_t)h * EMB))[tid];
  float4 b  = ((const float4*)(bv + (size_t)h * EMB))[tid];
  float a0 = __expf(bf2f(xr.x) - m.x) * is.x;
  float a1 = __expf(bf2f(xr.y) - m.y) * is.y;
  float a2 = __expf(bf2f(xr.z) - m.z) * is.z;
  float a3 = __expf(bf2f(xr.w) - m.w) * is.w;
  ushort4 o; o.x = f2bf(a0); o.y = f2bf(a1); o.z = f2bf(a2); o.w = f2bf(a3);
  ((ushort4*)(AT + rowoff))[tid] = o;
  float s = a0 * b.x + a1 * b.y + a2 * b.z + a3 * b.w;
  int lane = tid & 63, w = tid >> 6;
#pragma unroll
  for (int off = 32; off; off >>= 1) s += __shfl_down(s, off);
  if (lane == 0) sb[w] = s;
  __syncthreads();
  if (tid == 0) cbuf[h * EMB + f] = sb[0] + sb[1] + sb[2] + sb[3];
}

// ---------------------------------------------------------------- LN
// Xin is bf16 (GEMM MODE-5 output); stats in f32; residual f32.
__global__ __launch_bounds__(256) void layernorm_k(const unsigned short* __restrict__ Xin,
                                                   const float* __restrict__ resid,
                                                   const float* __restrict__ gw,
                                                   const float* __restrict__ bw,
                                                   float* __restrict__ outf,
                                                   unsigned short* __restrict__ outb) {
  __shared__ float sb[16];
  int row = blockIdx.x, tid = threadIdx.x;
  ushort4 xr = ((const ushort4*)(Xin + (size_t)row * EMB))[tid];
  float v0 = bf2f(xr.x), v1 = bf2f(xr.y), v2 = bf2f(xr.z), v3 = bf2f(xr.w);
  float s = v0 + v1 + v2 + v3;
  float q = v0 * v0 + v1 * v1 + v2 * v2 + v3 * v3;
  int lane = tid & 63, w = tid >> 6;
#pragma unroll
  for (int off = 32; off; off >>= 1) { s += __shfl_down(s, off); q += __shfl_down(q, off); }
  if (lane == 0) { sb[w] = s; sb[8 + w] = q; }
  __syncthreads();
  float mu  = (sb[0] + sb[1] + sb[2] + sb[3]) * (1.0f / EMB);
  float var = (sb[8] + sb[9] + sb[10] + sb[11]) * (1.0f / EMB) - mu * mu;
  float rs = rsqrtf(var + 1e-5f);
  float4 rv = ((const float4*)(resid + (size_t)row * EMB))[tid];
  float4 gv = ((const float4*)gw)[tid];
  float4 bv = ((const float4*)bw)[tid];
  float o0 = (v0 - mu) * rs * gv.x + bv.x + rv.x;
  float o1 = (v1 - mu) * rs * gv.y + bv.y + rv.y;
  float o2 = (v2 - mu) * rs * gv.z + bv.z + rv.z;
  float o3 = (v3 - mu) * rs * gv.w + bv.w + rv.w;
  float4 ov; ov.x = o0; ov.y = o1; ov.z = o2; ov.w = o3;
  ((float4*)(outf + (size_t)row * EMB))[tid] = ov;
  if (outb) {
    ushort4 ob; ob.x = f2bf(o0); ob.y = f2bf(o1); ob.z = f2bf(o2); ob.w = f2bf(o3);
    ((ushort4*)(outb + (size_t)row * EMB))[tid] = ob;
  }
}

// ---------------------------------------------------------------- launch
extern "C" void kernel_launch(void* const* d_in, const int* in_sizes, int n_in,
                              void* d_out, int out_size, void* d_ws, size_t ws_size,
                              hipStream_t stream) {
  const float* history = (const float*)d_in[0];
  const float* emb     = (const float*)d_in[1];
  const float* Wq_w = (const float*)d_in[2];
  const float* Wq_b = (const float*)d_in[3];
  const float* Wk_w = (const float*)d_in[4];
  const float* Wk_b = (const float*)d_in[5];
  const float* Wv_w = (const float*)d_in[6];
  const float* Wv_b = (const float*)d_in[7];
  const float* Wz_w = (const float*)d_in[8];
  const float* Wz_b = (const float*)d_in[9];
  const float* ln1_g = (const float*)d_in[10];
  const float* ln1_b = (const float*)d_in[11];
  const float* Wf_w = (const float*)d_in[12];
  const float* Wf_b = (const float*)d_in[13];
  const float* ln2_g = (const float*)d_in[14];
  const float* ln2_b = (const float*)d_in[15];

  char* ws = (char*)d_ws;
  const size_t MB = 1024ull * 1024ull;
  unsigned short* XT  = (unsigned short*)(ws + 0);        // [E][S] bf16, 8MB ; later LN1bf
  unsigned short* Ybf = (unsigned short*)(ws + 8 * MB);   // [S][E] bf16, 8MB
  unsigned short* Wkb = (unsigned short*)(ws + 16 * MB);  // [H][E][E] bf16, 16MB
  unsigned short* Wqb = (unsigned short*)(ws + 32 * MB);
  unsigned short* WvT = (unsigned short*)(ws + 48 * MB);  // [H][E'][E] transposed
  unsigned short* Wzb = (unsigned short*)(ws + 64 * MB);  // [E][H*E]
  unsigned short* Wfb = (unsigned short*)(ws + 80 * MB);  // [E][E], 2MB
  unsigned short* Gbf = (unsigned short*)(ws + 82 * MB);  // [E][E] bf16 (symmetric), 2MB
  float* xpart = (float*)(ws + 84 * MB);                  // 128 KB
  float* xbar  = (float*)(ws + 84 * MB + 160 * 1024);     // 4 KB
  float* ubuf  = (float*)(ws + 84 * MB + 192 * 1024);     // [H][E] 32 KB
  float* vbuf  = (float*)(ws + 84 * MB + 256 * 1024);
  float* cbuf  = (float*)(ws + 84 * MB + 320 * 1024);     // [H][E]
  float* dbuf  = (float*)(ws + 84 * MB + 384 * 1024);     // [E]
  unsigned short* Tbf = (unsigned short*)(ws + 85 * MB);  // 16MB; later Cbf, later FNbf
  float* Sc  = (float*)(ws + 101 * MB);                   // 32MB region: Gp/ScT/MpT (bf16)
  char*  St  = ws + 133 * MB;                             // stats; later Obf
  unsigned short* ATb = (unsigned short*)(ws + 149 * MB); // 16MB; later LN1 f32
  unsigned short* MTb = (unsigned short*)(ws + 165 * MB); // 2MB
  float* m_part = (float*)(St);                  // 512 KB [H][16][E]
  float* s_part = (float*)(St + 512 * 1024);     // 512 KB
  float* mfin   = (float*)(St + 1024 * 1024);    // 32 KB [H][E]
  float* isfin  = (float*)(St + 1056 * 1024);    // 32 KB
  // aliases (lifetimes verified non-overlapping)
  unsigned short* Gp  = (unsigned short*)Sc;  // [8][E][E] bf16 Gram partials
  unsigned short* ScT = (unsigned short*)Sc;  // [H][E][E] bf16 scoresT (after Gp)
  unsigned short* Cbf = Tbf;
  unsigned short* MpT = (unsigned short*)Sc;  // [H][E][E] bf16 (after ScT consumed)
  unsigned short* Obf = (unsigned short*)St;  // [S][E] bf16 (after stats consumed)
  float* LN1  = (float*)ATb;
  unsigned short* LN1b = XT;
  unsigned short* FNbf = Tbf;                 // [S][E] bf16 (after Cbf consumed)
  const long long EE = (long long)EMB * EMB;

  // --- colsum partials + emb/Wv transposes (one dispatch), then xbar
  colsum_xt_k<<<dim3(3200), 256, 0, stream>>>(emb, Wv_w, xpart, XT, WvT);
  colsum_red_k<<<dim3(4), 256, 0, stream>>>(xpart, xbar);

  // --- FUSED: split-K symmetric Gram + remaining conversions
  gram_cvt_k<<<dim3(6336), 256, 0, stream>>>(XT, Gp,
                                             Wk_w, Wq_w, history, Wz_w, Wf_w,
                                             xbar,
                                             Wkb, Wqb, Ybf, Wzb, Wfb,
                                             ubuf, vbuf);
  plane_red_k<<<dim3(EMB * EMB / 4 / 256), 256, 0, stream>>>(Gp, Gbf);
  // --- T2_h = Wq_h * G  (G symmetric; NT B-operand)
  gemm_nt<1><<<dim3(1024), 256, 0, stream>>>(Wqb, Gbf, Tbf, EMB, EMB, EMB, EMB,
                                             EE, 0, EE, 16, 8,
                                             nullptr, nullptr, nullptr, nullptr,
                                             nullptr, nullptr);
  // --- scoresT_h = (T2_h * Wk_h^T + rank-1)/32 -> bf16 + col-stat partials
  gemm_nt<4><<<dim3(1024), 256, 0, stream>>>(Tbf, Wkb, ScT, EMB, EMB, EMB, EMB,
                                             EE, EE, EE, 16, 8,
                                             Wq_b, ubuf, Wk_b, vbuf,
                                             m_part, s_part);
  // --- merge column softmax stats (32 blocks, done once)
  colstat2_k<<<dim3(32), 256, 0, stream>>>(m_part, s_part, mfin, isfin);
  // --- AT = exp(scoresT - m)*is (bf16) fused with cvec dot
  at_cvec_k<<<dim3(EMB, NH), 256, 0, stream>>>(ScT, mfin, isfin, Wv_b, ATb, cbuf);
  // --- C_h = WvT_h * AT_h^T  == Wv_h^T A_h
  gemm_nt<1><<<dim3(1024), 256, 0, stream>>>(WvT, ATb, Cbf, EMB, EMB, EMB, EMB,
                                             EE, EE, EE, 16, 8,
                                             nullptr, nullptr, nullptr, nullptr,
                                             nullptr, nullptr);
  // --- FUSED: MpT_h = Wz_h * C_h^T + dvec
  mp_dvec_k<<<dim3(2048), 256, 0, stream>>>(Cbf, Wzb, MpT, Wz_b, cbuf, dbuf);
  // --- MT = sum_h MpT_h (plain 8-plane reduction, no transpose)
  plane_red_k<<<dim3(EMB * EMB / 4 / 256), 256, 0, stream>>>(MpT, MTb);
  // --- O = Y * M + d  (bf16 out; stats region consumed already)
  gemm_nt<5><<<dim3(512), 256, 0, stream>>>(Ybf, MTb, Obf, EMB, EMB, EMB, EMB,
                                            0, 0, 0, 64, 8,
                                            dbuf, nullptr, nullptr, nullptr,
                                            nullptr, nullptr);
  // --- LN1 = LN(O)+emb (f32 + bf16 copies)
  layernorm_k<<<dim3(SEQ), 256, 0, stream>>>(Obf, emb, ln1_g, ln1_b, LN1, LN1b);
  // --- FN = LN1 * Wf^T + bf  (bf16 out, overwrites Cbf region)
  gemm_nt<5><<<dim3(512), 256, 0, stream>>>(LN1b, Wfb, FNbf, EMB, EMB, EMB, EMB,
                                            0, 0, 0, 64, 8,
                                            Wf_b, nullptr, nullptr, nullptr,
                                            nullptr, nullptr);
  // --- out = LN(FN)+LN1
  layernorm_k<<<dim3(SEQ), 256, 0, stream>>>(FNbf, LN1, ln2_g, ln2_b, (float*)d_out, nullptr);
}

// Round 22
// 262.692 us; speedup vs baseline: 1.1241x; 1.0159x over previous
//
#include <hip/hip_runtime.h>

// AutoDecoderLayer on MI355X.
// Algebra: with X=embdding, Y=history,
//   G = X^T X ; scoresT_h = (Wq_h G Wk_h^T + rank-1 bias)/32 (= scores^T)
//   AT_h = colsoftmax(scoresT_h) ; c_h = AT_h bv_h
//   M = sum_h Wv_h^T A_h Wz_h^T ;  d = bz + (Wz c)
//   O = Y M + d ; LN1 = LN(O)+X ; FN = LN1 Wf^T + bf ; out = LN(FN)+LN1
// R20: split-K symmetric Gram + MpT operand swap + plane_red (266.9us).
// R21: LN1 kept ONLY in bf16 — mid-LN writes bf16, final LN reads the bf16
// residual. Deletes the 16MB f32 LN1 write + 16MB read (~5us). Error from
// bf16 residual <= ~0.008 absolute (margin 3x).

constexpr int EMB = 1024;
constexpr int SEQ = 4096;
constexpr int NH  = 8;

using f32x4  = __attribute__((ext_vector_type(4))) float;
using bf16x8 = __attribute__((ext_vector_type(8))) __bf16;
using us8    = __attribute__((ext_vector_type(8))) unsigned short;
using us4    = __attribute__((ext_vector_type(4))) unsigned short;

#define GLOAD_LDS16(g, l) __builtin_amdgcn_global_load_lds(                 \
    (const __attribute__((address_space(1))) void*)(g),                     \
    (__attribute__((address_space(3))) void*)(l), 16, 0, 0)

__device__ inline unsigned short f2bf(float x) {
  unsigned int u = __float_as_uint(x);
  u += 0x7FFFu + ((u >> 16) & 1u);   // round-to-nearest-even
  return (unsigned short)(u >> 16);
}
__device__ inline float bf2f(unsigned short h) {
  return __uint_as_float(((unsigned int)h) << 16);
}
__device__ inline f32x4 ntl4(const float* p) {
  return __builtin_nontemporal_load((const f32x4*)p);
}
__device__ inline us4 cvt4(f32x4 x) {
  us4 o; o[0] = f2bf(x[0]); o[1] = f2bf(x[1]); o[2] = f2bf(x[2]); o[3] = f2bf(x[3]);
  return o;
}

// ---------------------------------------------------------------- GEMM body
// C[m,n] = sum_k A[m*lda+k] * B[n*ldb+k], bf16 in, f32 acc.
// 64x128 tile, BK=64, 4 waves (2x2), single-buffered 24KB LDS, async
// global_load_lds staging. MODE 1: bf16 store. 2: bf16 store + transposed
// MIRROR store (symmetric Gram). 4: scoresT bf16 + col-softmax partials.
// 5: bf16 store + bias[n]. bx/by/z pre-decoded by caller.
template <int MODE>
__device__ __attribute__((always_inline)) void gemm_body(
    unsigned short* lds, int bx, int by, int z,
    const unsigned short* A, const unsigned short* B, void* Cout,
    int K, int lda, int ldb, int ldc,
    long long aZ, long long bZ, long long cZ,
    const float* e0, const float* e1, const float* e2, const float* e3,
    float* mpart, float* spart) {
  A += (size_t)z * aZ;
  B += (size_t)z * bZ;
  const int tid = threadIdx.x;
  const int lane = tid & 63, wid = tid >> 6;
  const int wm = wid >> 1, wn = wid & 1;     // 2x2 wave grid
  const int row0 = bx * 64, col0 = by * 128;

  unsigned short* As = lds;                  // [64][64]  8KB
  unsigned short* Bs = lds + 64 * 64;        // [128][64] 16KB

  f32x4 acc[2][4] = {};
  const int lrow = lane & 15, kg = lane >> 4;
  const int lr = lane >> 3;        // row within an 8-row chunk
  const int lc = (lane & 7) * 8;   // elem col within 64

  const int nt = K >> 6;
  for (int t = 0; t < nt; ++t) {
    const int k0 = t << 6;
#pragma unroll
    for (int c = 0; c < 2; ++c) {
      int chunk = wid * 2 + c;
      int r = chunk * 8 + lr;
      GLOAD_LDS16(A + (size_t)(row0 + r) * lda + k0 + lc, &As[chunk * 512]);
    }
#pragma unroll
    for (int c = 0; c < 4; ++c) {
      int chunk = wid * 4 + c;
      int r = chunk * 8 + lr;
      GLOAD_LDS16(B + (size_t)(col0 + r) * ldb + k0 + lc, &Bs[chunk * 512]);
    }
    __syncthreads();
#pragma unroll
    for (int ks = 0; ks < 2; ++ks) {
      bf16x8 a[2], b[4];
      int koff = ks * 32 + kg * 8;
#pragma unroll
      for (int i = 0; i < 2; ++i)
        a[i] = *(const bf16x8*)&As[(wm * 32 + i * 16 + lrow) * 64 + koff];
#pragma unroll
      for (int j = 0; j < 4; ++j)
        b[j] = *(const bf16x8*)&Bs[(wn * 64 + j * 16 + lrow) * 64 + koff];
#pragma unroll
      for (int i = 0; i < 2; ++i)
#pragma unroll
        for (int j = 0; j < 4; ++j)
          acc[i][j] = __builtin_amdgcn_mfma_f32_16x16x32_bf16(a[i], b[j], acc[i][j], 0, 0, 0);
    }
    __syncthreads();
  }

  const int rb = (lane >> 4) * 4, cc = lane & 15;
  unsigned short* Cs = lds;                // [64][128] 16KB
#pragma unroll
  for (int i = 0; i < 2; ++i) {
#pragma unroll
    for (int j = 0; j < 4; ++j) {
#pragma unroll
      for (int r = 0; r < 4; ++r) {
        float val = acc[i][j][r];
        int mm = wm * 32 + i * 16 + rb + r;
        int nn = wn * 64 + j * 16 + cc;
        if (MODE == 4) {
          int m = row0 + mm, n = col0 + nn;
          float bq = e0[z * EMB + m], uu = e1[z * EMB + n];
          float bk = e2[z * EMB + n], vv = e3[z * EMB + m];
          val = (val + bq * (uu + (float)SEQ * bk) + vv * bk) * (1.0f / 32.0f);
        } else if (MODE == 5) {
          val += e0[col0 + nn];
        }
        Cs[mm * 128 + nn] = f2bf(val);
      }
    }
  }
  __syncthreads();
  unsigned short* Cg = (unsigned short*)Cout + (size_t)z * cZ;
#pragma unroll
  for (int p = 0; p < 4; ++p) {
    int idx = p * 256 + tid;
    int row = idx >> 4, col = (idx & 15) * 8;
    *(us8*)(Cg + (size_t)(row0 + row) * ldc + col0 + col) =
        *(const us8*)&Cs[row * 128 + col];
  }
  if (MODE == 2) {
    // mirror store: G[col0+nn][row0+mm] = Cs[mm][nn] (identical values at
    // overlaps -> benign). 128 rows x 64 cols, us8 chunks (8 bf16).
#pragma unroll
    for (int p = 0; p < 4; ++p) {
      int idx = p * 256 + tid;               // 1024 chunks
      int rr = idx >> 3;                     // mirror row: nn in [0,128)
      int cg = (idx & 7) * 8;                // mirror col group: mm base
      us8 o;
#pragma unroll
      for (int e = 0; e < 8; ++e) o[e] = Cs[(cg + e) * 128 + rr];
      *(us8*)(Cg + (size_t)(col0 + rr) * ldc + row0 + cg) = o;
    }
  }
  if (MODE == 4) {
    // column softmax partials over this tile's 64 rows (2 threads/col),
    // computed from the SAME bf16 values at_cvec will read back.
    int colx = tid >> 1, half = tid & 1;
    float mx = -1e30f;
#pragma unroll 8
    for (int r = 0; r < 32; ++r)
      mx = fmaxf(mx, bf2f(Cs[(half * 32 + r) * 128 + colx]));
    mx = fmaxf(mx, __shfl_xor(mx, 1));
    float se = 0.f;
#pragma unroll 8
    for (int r = 0; r < 32; ++r)
      se += __expf(bf2f(Cs[(half * 32 + r) * 128 + colx]) - mx);
    se += __shfl_xor(se, 1);
    if (half == 0) {
      size_t soff = ((size_t)z * 16 + bx) * EMB + col0 + colx;
      mpart[soff] = mx;
      spart[soff] = se;
    }
  }
}

template <int MODE>
__global__ __launch_bounds__(256) void gemm_nt(const unsigned short* __restrict__ A,
                                               const unsigned short* __restrict__ B,
                                               void* __restrict__ Cout,
                                               int K, int lda, int ldb, int ldc,
                                               long long aZ, long long bZ, long long cZ,
                                               int nx, int ny,
                                               const float* __restrict__ e0,
                                               const float* __restrict__ e1,
                                               const float* __restrict__ e2,
                                               const float* __restrict__ e3,
                                               float* __restrict__ mpart,
                                               float* __restrict__ spart) {
  __shared__ __align__(16) unsigned short lds[(64 + 128) * 64];
  const int q = gridDim.x >> 3;                       // nwg % 8 == 0
  const int wg = (blockIdx.x & 7) * q + (blockIdx.x >> 3);
  const int bx = wg % nx, by = (wg / nx) % ny, z = wg / (nx * ny);
  gemm_body<MODE>(lds, bx, by, z, A, B, Cout, K, lda, ldb, ldc, aZ, bZ, cZ,
                  e0, e1, e2, e3, mpart, spart);
}

// ------------------- colsum_part + emb-transpose + Wv-transpose (one dispatch)
// [0,128): colsum partials; [128,1152): emb 64x64 tiles -> XT;
// [1152,3200): Wv 64x64 tiles -> WvT
__global__ __launch_bounds__(256) void colsum_xt_k(const float* __restrict__ emb,
                                                   const float* __restrict__ Wv,
                                                   float* __restrict__ part,
                                                   unsigned short* __restrict__ XT,
                                                   unsigned short* __restrict__ WvT) {
  __shared__ float tileT[64][65];
  const int b = blockIdx.x, tid = threadIdx.x;
  if (b < 128) {
    int e = (b & 3) * 256 + tid;
    int y = b >> 2;
    float s = 0.f;
    for (int r = y * 128; r < y * 128 + 128; ++r) s += emb[(size_t)r * EMB + e];
    part[y * EMB + e] = s;
    return;
  }
  const float* src; unsigned short* dst; int R, r0, c0;
  if (b < 1152) {
    int tb = b - 128;                      // emb [4096][1024] -> XT [1024][4096]
    src = emb; dst = XT; R = SEQ;
    r0 = (tb >> 4) * 64; c0 = (tb & 15) * 64;
  } else {
    int t2 = b - 1152, z = t2 >> 8, tt = t2 & 255;
    src = Wv + (size_t)z * EMB * EMB; dst = WvT + (size_t)z * EMB * EMB;
    R = EMB;
    r0 = (tt >> 4) * 64; c0 = (tt & 15) * 64;
  }
  int tx = tid & 15, ty = tid >> 4;        // 16 x 16 threads
#pragma unroll
  for (int p = 0; p < 4; ++p) {            // NT float4 loads, transposed scatter
    int ir = p * 16 + ty;
    f32x4 x = ntl4(src + (size_t)(r0 + ir) * EMB + c0 + tx * 4);
    tileT[tx * 4 + 0][ir] = x[0]; tileT[tx * 4 + 1][ir] = x[1];
    tileT[tx * 4 + 2][ir] = x[2]; tileT[tx * 4 + 3][ir] = x[3];
  }
  __syncthreads();
#pragma unroll
  for (int p = 0; p < 4; ++p) {            // contiguous LDS read, normal stores
    int orow = p * 16 + ty;
    f32x4 x;
    x[0] = tileT[orow][tx * 4 + 0]; x[1] = tileT[orow][tx * 4 + 1];
    x[2] = tileT[orow][tx * 4 + 2]; x[3] = tileT[orow][tx * 4 + 3];
    *(us4*)(dst + (size_t)(c0 + orow) * R + r0 + tx * 4) = cvt4(x);
  }
}

__global__ __launch_bounds__(256) void colsum_red_k(const float* __restrict__ part,
                                                    float* __restrict__ xbar) {
  int e = blockIdx.x * 256 + threadIdx.x;
  float s = 0.f;
  for (int y = 0; y < 32; ++y) s += part[y * EMB + e];
  xbar[e] = s;
}

// -------- FUSED: split-K symmetric Gram GEMM (blocks [0,576)) + conversions
// Gram: 72 tiles (bx>=2by) x 8 z, K=512 each, mirror-stored into Gp.
// GEMM blocks first so the (bx&7) swizzle aligns with round-robin XCDs.
// [576,4672)   Wk/Wq: one row per wave -> bf16 + dot(xbar) -> u/v
// [4672,6336)  flat conversions, 8192 f32/block: hist | Wz | Wf
__global__ __launch_bounds__(256) void gram_cvt_k(
    const unsigned short* __restrict__ XT, unsigned short* __restrict__ Gp,
    const float* __restrict__ Wk, const float* __restrict__ Wq,
    const float* __restrict__ hist, const float* __restrict__ Wz,
    const float* __restrict__ Wf, const float* __restrict__ xbar,
    unsigned short* __restrict__ Wkb, unsigned short* __restrict__ Wqb,
    unsigned short* __restrict__ Yb, unsigned short* __restrict__ Wzb,
    unsigned short* __restrict__ Wfb,
    float* __restrict__ u, float* __restrict__ v) {
  __shared__ __align__(16) unsigned short smem[(64 + 128) * 64];  // 24KB union
  const int tid = threadIdx.x;
  if (blockIdx.x < 576) {
    const int wg = ((int)blockIdx.x & 7) * 72 + ((int)blockIdx.x >> 3);
    const int t = wg % 72, z = wg / 72;
    // decode t -> (bx,by): starts[by] = 16by - by(by-1)
    int by = 0, st = 0;
#pragma unroll
    for (int b = 7; b >= 1; --b) {
      int sb = 16 * b - b * (b - 1);
      if (t >= sb && by == 0) { by = b; st = sb; }
    }
    int bx = 2 * by + (t - st);
    gemm_body<2>(smem, bx, by, z, XT, XT, Gp, 512, SEQ, SEQ, EMB,
                 512, 512, (long long)EMB * EMB,
                 nullptr, nullptr, nullptr, nullptr, nullptr, nullptr);
    return;
  }
  int c = blockIdx.x - 576;
  if (c < 4096) {                        // cvt + xbar-dot, one row per wave
    int gw = c * 4 + (tid >> 6);
    int lane = tid & 63;
    const float* src = (gw < 8192) ? Wk : Wq;
    unsigned short* dst = (gw < 8192) ? Wkb : Wqb;
    float* dot = (gw < 8192) ? u : v;
    int row = gw & 8191;
    const float* sr = src + (size_t)row * EMB;
    const float4* xb4 = (const float4*)xbar;
    unsigned short* dr = dst + (size_t)row * EMB;
    float s = 0.f;
#pragma unroll
    for (int j = 0; j < 4; ++j) {
      int idx = j * 64 + lane;
      f32x4 x = ntl4(sr + idx * 4);
      float4 xb = xb4[idx];
      *(us4*)(dr + idx * 4) = cvt4(x);
      s += x[0] * xb.x + x[1] * xb.y + x[2] * xb.z + x[3] * xb.w;
    }
#pragma unroll
    for (int off = 32; off; off >>= 1) s += __shfl_down(s, off);
    if (lane == 0) dot[row] = s;
  } else {                               // flat conversions, 8192 f32/block
    size_t f0 = (size_t)(c - 4096) * 8192;
    const float* src; unsigned short* dst; size_t loc;
    if (f0 < 4194304ull) { src = hist; dst = Yb; loc = f0; }
    else if (f0 < 12582912ull) { src = Wz; dst = Wzb; loc = f0 - 4194304ull; }
    else { src = Wf; dst = Wfb; loc = f0 - 12582912ull; }
#pragma unroll
    for (int p = 0; p < 8; ++p) {
      int i = p * 256 + tid;
      f32x4 x = ntl4(src + loc + i * 4);
      *(us4*)(dst + loc + i * 4) = cvt4(x);
    }
  }
}

// ------- FUSED: MpT GEMM (blocks [0,1024)) + dvec.  MpT_h = Wz_h * C_h^T
// (A = Wzb rows, lda=8192, head offset aZ=EMB in k; B = Cbf planes).
__global__ __launch_bounds__(256) void mp_dvec_k(
    const unsigned short* __restrict__ Cbf, const unsigned short* __restrict__ Wzb,
    unsigned short* __restrict__ MpT,
    const float* __restrict__ bz, const float* __restrict__ cvec,
    float* __restrict__ d) {
  __shared__ __align__(16) unsigned short smem[(64 + 128) * 64];
  const int tid = threadIdx.x;
  if (blockIdx.x < 1024) {
    const int wg = ((int)blockIdx.x & 7) * 128 + ((int)blockIdx.x >> 3);
    const int bx = wg % 16, by = (wg / 16) % 8, z = wg / 128;
    gemm_body<1>(smem, bx, by, z, Wzb, Cbf, MpT, EMB, NH * EMB, EMB, EMB,
                 (long long)EMB, (long long)EMB * EMB, (long long)EMB * EMB,
                 nullptr, nullptr, nullptr, nullptr, nullptr, nullptr);
    return;
  }
  // dvec: d[g] = bz[g] + dot(Wzb[g,:], cvec)
  int g = blockIdx.x - 1024;
  float* sb = (float*)smem;
  const unsigned short* row = Wzb + (size_t)g * (NH * EMB);
  float s = 0.f;
#pragma unroll
  for (int p = 0; p < 4; ++p) {
    int i = p * 256 + tid;
    us8 w = ((const us8*)row)[i];
    float4 c0 = ((const float4*)cvec)[i * 2];
    float4 c1 = ((const float4*)cvec)[i * 2 + 1];
    s += bf2f(w[0]) * c0.x + bf2f(w[1]) * c0.y + bf2f(w[2]) * c0.z + bf2f(w[3]) * c0.w;
    s += bf2f(w[4]) * c1.x + bf2f(w[5]) * c1.y + bf2f(w[6]) * c1.z + bf2f(w[7]) * c1.w;
  }
  int lane = tid & 63, w = tid >> 6;
#pragma unroll
  for (int off = 32; off; off >>= 1) s += __shfl_down(s, off);
  if (lane == 0) sb[w] = s;
  __syncthreads();
  if (tid == 0) d[g] = bz[g] + sb[0] + sb[1] + sb[2] + sb[3];
}

// out[i] = bf16( sum_z in[z][i] ), 8 bf16 planes (Gp->Gbf, MpT->MT)
__global__ __launch_bounds__(256) void plane_red_k(const unsigned short* __restrict__ in,
                                                   unsigned short* __restrict__ out) {
  int i = blockIdx.x * 256 + threadIdx.x;  // ushort4 index
  float4 s = {0.f, 0.f, 0.f, 0.f};
#pragma unroll
  for (int z = 0; z < 8; ++z) {
    ushort4 v = ((const ushort4*)(in + (size_t)z * EMB * EMB))[i];
    s.x += bf2f(v.x); s.y += bf2f(v.y); s.z += bf2f(v.z); s.w += bf2f(v.w);
  }
  ushort4 o; o.x = f2bf(s.x); o.y = f2bf(s.y); o.z = f2bf(s.z); o.w = f2bf(s.w);
  ((ushort4*)out)[i] = o;
}

// ------------------------------------------- transposed-softmax pipeline
__global__ __launch_bounds__(256) void colstat2_k(const float* __restrict__ m_part,
                                                  const float* __restrict__ s_part,
                                                  float* __restrict__ mfin,
                                                  float* __restrict__ isfin) {
  int i = blockIdx.x * 256 + threadIdx.x;     // (h,col) flat, grid = 32
  int h = i >> 10, col = i & 1023;
  float M = -1e30f, S = 0.f;
#pragma unroll
  for (int c = 0; c < 16; ++c) {
    float m = m_part[((size_t)h * 16 + c) * EMB + col];
    float s = s_part[((size_t)h * 16 + c) * EMB + col];
    float nm = fmaxf(M, m);
    S = S * __expf(M - nm) + s * __expf(m - nm);
    M = nm;
  }
  mfin[i] = M;
  isfin[i] = 1.0f / S;
}

__global__ __launch_bounds__(256) void at_cvec_k(const unsigned short* __restrict__ ScT,
                                                 const float* __restrict__ mfin,
                                                 const float* __restrict__ isfin,
                                                 const float* __restrict__ bv,
                                                 unsigned short* __restrict__ AT,
                                                 float* __restrict__ cbuf) {
  __shared__ float sb[4];
  int f = blockIdx.x, h = blockIdx.y, tid = threadIdx.x;
  size_t rowoff = ((size_t)h * EMB + f) * EMB;
  ushort4 xr = ((const ushort4*)(ScT + rowoff))[tid];
  float4 m  = ((const float4*)(mfin + (size_t)h * EMB))[tid];
  float4 is = ((const float4*)(isfin + (size_t)h * EMB))[tid];
  float4 b  = ((const float4*)(bv + (size_t)h * EMB))[tid];
  float a0 = __expf(bf2f(xr.x) - m.x) * is.x;
  float a1 = __expf(bf2f(xr.y) - m.y) * is.y;
  float a2 = __expf(bf2f(xr.z) - m.z) * is.z;
  float a3 = __expf(bf2f(xr.w) - m.w) * is.w;
  ushort4 o; o.x = f2bf(a0); o.y = f2bf(a1); o.z = f2bf(a2); o.w = f2bf(a3);
  ((ushort4*)(AT + rowoff))[tid] = o;
  float s = a0 * b.x + a1 * b.y + a2 * b.z + a3 * b.w;
  int lane = tid & 63, w = tid >> 6;
#pragma unroll
  for (int off = 32; off; off >>= 1) s += __shfl_down(s, off);
  if (lane == 0) sb[w] = s;
  __syncthreads();
  if (tid == 0) cbuf[h * EMB + f] = sb[0] + sb[1] + sb[2] + sb[3];
}

// ---------------------------------------------------------------- LN
// mid-LN: Xin bf16, residual f32, OUTPUT bf16 ONLY (LN1 lives only in bf16).
__global__ __launch_bounds__(256) void ln_mid_k(const unsigned short* __restrict__ Xin,
                                                const float* __restrict__ resid,
                                                const float* __restrict__ gw,
                                                const float* __restrict__ bw,
                                                unsigned short* __restrict__ outb) {
  __shared__ float sb[16];
  int row = blockIdx.x, tid = threadIdx.x;
  ushort4 xr = ((const ushort4*)(Xin + (size_t)row * EMB))[tid];
  float v0 = bf2f(xr.x), v1 = bf2f(xr.y), v2 = bf2f(xr.z), v3 = bf2f(xr.w);
  float s = v0 + v1 + v2 + v3;
  float q = v0 * v0 + v1 * v1 + v2 * v2 + v3 * v3;
  int lane = tid & 63, w = tid >> 6;
#pragma unroll
  for (int off = 32; off; off >>= 1) { s += __shfl_down(s, off); q += __shfl_down(q, off); }
  if (lane == 0) { sb[w] = s; sb[8 + w] = q; }
  __syncthreads();
  float mu  = (sb[0] + sb[1] + sb[2] + sb[3]) * (1.0f / EMB);
  float var = (sb[8] + sb[9] + sb[10] + sb[11]) * (1.0f / EMB) - mu * mu;
  float rs = rsqrtf(var + 1e-5f);
  float4 rv = ((const float4*)(resid + (size_t)row * EMB))[tid];
  float4 gv = ((const float4*)gw)[tid];
  float4 bv = ((const float4*)bw)[tid];
  ushort4 ob;
  ob.x = f2bf((v0 - mu) * rs * gv.x + bv.x + rv.x);
  ob.y = f2bf((v1 - mu) * rs * gv.y + bv.y + rv.y);
  ob.z = f2bf((v2 - mu) * rs * gv.z + bv.z + rv.z);
  ob.w = f2bf((v3 - mu) * rs * gv.w + bv.w + rv.w);
  ((ushort4*)(outb + (size_t)row * EMB))[tid] = ob;
}

// final LN: Xin bf16, residual bf16, output f32 (d_out).
__global__ __launch_bounds__(256) void ln_out_k(const unsigned short* __restrict__ Xin,
                                                const unsigned short* __restrict__ resid,
                                                const float* __restrict__ gw,
                                                const float* __restrict__ bw,
                                                float* __restrict__ outf) {
  __shared__ float sb[16];
  int row = blockIdx.x, tid = threadIdx.x;
  ushort4 xr = ((const ushort4*)(Xin + (size_t)row * EMB))[tid];
  float v0 = bf2f(xr.x), v1 = bf2f(xr.y), v2 = bf2f(xr.z), v3 = bf2f(xr.w);
  float s = v0 + v1 + v2 + v3;
  float q = v0 * v0 + v1 * v1 + v2 * v2 + v3 * v3;
  int lane = tid & 63, w = tid >> 6;
#pragma unroll
  for (int off = 32; off; off >>= 1) { s += __shfl_down(s, off); q += __shfl_down(q, off); }
  if (lane == 0) { sb[w] = s; sb[8 + w] = q; }
  __syncthreads();
  float mu  = (sb[0] + sb[1] + sb[2] + sb[3]) * (1.0f / EMB);
  float var = (sb[8] + sb[9] + sb[10] + sb[11]) * (1.0f / EMB) - mu * mu;
  float rs = rsqrtf(var + 1e-5f);
  ushort4 rr = ((const ushort4*)(resid + (size_t)row * EMB))[tid];
  float4 gv = ((const float4*)gw)[tid];
  float4 bv = ((const float4*)bw)[tid];
  float4 ov;
  ov.x = (v0 - mu) * rs * gv.x + bv.x + bf2f(rr.x);
  ov.y = (v1 - mu) * rs * gv.y + bv.y + bf2f(rr.y);
  ov.z = (v2 - mu) * rs * gv.z + bv.z + bf2f(rr.z);
  ov.w = (v3 - mu) * rs * gv.w + bv.w + bf2f(rr.w);
  ((float4*)(outf + (size_t)row * EMB))[tid] = ov;
}

// ---------------------------------------------------------------- launch
extern "C" void kernel_launch(void* const* d_in, const int* in_sizes, int n_in,
                              void* d_out, int out_size, void* d_ws, size_t ws_size,
                              hipStream_t stream) {
  const float* history = (const float*)d_in[0];
  const float* emb     = (const float*)d_in[1];
  const float* Wq_w = (const float*)d_in[2];
  const float* Wq_b = (const float*)d_in[3];
  const float* Wk_w = (const float*)d_in[4];
  const float* Wk_b = (const float*)d_in[5];
  const float* Wv_w = (const float*)d_in[6];
  const float* Wv_b = (const float*)d_in[7];
  const float* Wz_w = (const float*)d_in[8];
  const float* Wz_b = (const float*)d_in[9];
  const float* ln1_g = (const float*)d_in[10];
  const float* ln1_b = (const float*)d_in[11];
  const float* Wf_w = (const float*)d_in[12];
  const float* Wf_b = (const float*)d_in[13];
  const float* ln2_g = (const float*)d_in[14];
  const float* ln2_b = (const float*)d_in[15];

  char* ws = (char*)d_ws;
  const size_t MB = 1024ull * 1024ull;
  unsigned short* XT  = (unsigned short*)(ws + 0);        // [E][S] bf16, 8MB ; later LN1b
  unsigned short* Ybf = (unsigned short*)(ws + 8 * MB);   // [S][E] bf16, 8MB
  unsigned short* Wkb = (unsigned short*)(ws + 16 * MB);  // [H][E][E] bf16, 16MB
  unsigned short* Wqb = (unsigned short*)(ws + 32 * MB);
  unsigned short* WvT = (unsigned short*)(ws + 48 * MB);  // [H][E'][E] transposed
  unsigned short* Wzb = (unsigned short*)(ws + 64 * MB);  // [E][H*E]
  unsigned short* Wfb = (unsigned short*)(ws + 80 * MB);  // [E][E], 2MB
  unsigned short* Gbf = (unsigned short*)(ws + 82 * MB);  // [E][E] bf16 (symmetric), 2MB
  float* xpart = (float*)(ws + 84 * MB);                  // 128 KB
  float* xbar  = (float*)(ws + 84 * MB + 160 * 1024);     // 4 KB
  float* ubuf  = (float*)(ws + 84 * MB + 192 * 1024);     // [H][E] 32 KB
  float* vbuf  = (float*)(ws + 84 * MB + 256 * 1024);
  float* cbuf  = (float*)(ws + 84 * MB + 320 * 1024);     // [H][E]
  float* dbuf  = (float*)(ws + 84 * MB + 384 * 1024);     // [E]
  unsigned short* Tbf = (unsigned short*)(ws + 85 * MB);  // 16MB; later Cbf, later FNbf
  float* Sc  = (float*)(ws + 101 * MB);                   // 32MB region: Gp/ScT/MpT (bf16)
  char*  St  = ws + 133 * MB;                             // stats; later Obf
  unsigned short* ATb = (unsigned short*)(ws + 149 * MB); // 16MB
  unsigned short* MTb = (unsigned short*)(ws + 165 * MB); // 2MB
  float* m_part = (float*)(St);                  // 512 KB [H][16][E]
  float* s_part = (float*)(St + 512 * 1024);     // 512 KB
  float* mfin   = (float*)(St + 1024 * 1024);    // 32 KB [H][E]
  float* isfin  = (float*)(St + 1056 * 1024);    // 32 KB
  // aliases (lifetimes verified non-overlapping)
  unsigned short* Gp  = (unsigned short*)Sc;  // [8][E][E] bf16 Gram partials
  unsigned short* ScT = (unsigned short*)Sc;  // [H][E][E] bf16 scoresT (after Gp)
  unsigned short* Cbf = Tbf;
  unsigned short* MpT = (unsigned short*)Sc;  // [H][E][E] bf16 (after ScT consumed)
  unsigned short* Obf = (unsigned short*)St;  // [S][E] bf16 (after stats consumed)
  unsigned short* LN1b = XT;                  // [S][E] bf16 (XT dead after Gram)
  unsigned short* FNbf = Tbf;                 // [S][E] bf16 (after Cbf consumed)
  const long long EE = (long long)EMB * EMB;

  // --- colsum partials + emb/Wv transposes (one dispatch), then xbar
  colsum_xt_k<<<dim3(3200), 256, 0, stream>>>(emb, Wv_w, xpart, XT, WvT);
  colsum_red_k<<<dim3(4), 256, 0, stream>>>(xpart, xbar);

  // --- FUSED: split-K symmetric Gram + remaining conversions
  gram_cvt_k<<<dim3(6336), 256, 0, stream>>>(XT, Gp,
                                             Wk_w, Wq_w, history, Wz_w, Wf_w,
                                             xbar,
                                             Wkb, Wqb, Ybf, Wzb, Wfb,
                                             ubuf, vbuf);
  plane_red_k<<<dim3(EMB * EMB / 4 / 256), 256, 0, stream>>>(Gp, Gbf);
  // --- T2_h = Wq_h * G  (G symmetric; NT B-operand)
  gemm_nt<1><<<dim3(1024), 256, 0, stream>>>(Wqb, Gbf, Tbf, EMB, EMB, EMB, EMB,
                                             EE, 0, EE, 16, 8,
                                             nullptr, nullptr, nullptr, nullptr,
                                             nullptr, nullptr);
  // --- scoresT_h = (T2_h * Wk_h^T + rank-1)/32 -> bf16 + col-stat partials
  gemm_nt<4><<<dim3(1024), 256, 0, stream>>>(Tbf, Wkb, ScT, EMB, EMB, EMB, EMB,
                                             EE, EE, EE, 16, 8,
                                             Wq_b, ubuf, Wk_b, vbuf,
                                             m_part, s_part);
  // --- merge column softmax stats (32 blocks, done once)
  colstat2_k<<<dim3(32), 256, 0, stream>>>(m_part, s_part, mfin, isfin);
  // --- AT = exp(scoresT - m)*is (bf16) fused with cvec dot
  at_cvec_k<<<dim3(EMB, NH), 256, 0, stream>>>(ScT, mfin, isfin, Wv_b, ATb, cbuf);
  // --- C_h = WvT_h * AT_h^T  == Wv_h^T A_h
  gemm_nt<1><<<dim3(1024), 256, 0, stream>>>(WvT, ATb, Cbf, EMB, EMB, EMB, EMB,
                                             EE, EE, EE, 16, 8,
                                             nullptr, nullptr, nullptr, nullptr,
                                             nullptr, nullptr);
  // --- FUSED: MpT_h = Wz_h * C_h^T + dvec
  mp_dvec_k<<<dim3(2048), 256, 0, stream>>>(Cbf, Wzb, MpT, Wz_b, cbuf, dbuf);
  // --- MT = sum_h MpT_h (plain 8-plane reduction, no transpose)
  plane_red_k<<<dim3(EMB * EMB / 4 / 256), 256, 0, stream>>>(MpT, MTb);
  // --- O = Y * M + d  (bf16 out; stats region consumed already)
  gemm_nt<5><<<dim3(512), 256, 0, stream>>>(Ybf, MTb, Obf, EMB, EMB, EMB, EMB,
                                            0, 0, 0, 64, 8,
                                            dbuf, nullptr, nullptr, nullptr,
                                            nullptr, nullptr);
  // --- LN1 = LN(O)+emb  (bf16 ONLY)
  ln_mid_k<<<dim3(SEQ), 256, 0, stream>>>(Obf, emb, ln1_g, ln1_b, LN1b);
  // --- FN = LN1 * Wf^T + bf  (bf16 out, overwrites Cbf region)
  gemm_nt<5><<<dim3(512), 256, 0, stream>>>(LN1b, Wfb, FNbf, EMB, EMB, EMB, EMB,
                                            0, 0, 0, 64, 8,
                                            Wf_b, nullptr, nullptr, nullptr,
                                            nullptr, nullptr);
  // --- out = LN(FN)+LN1  (bf16 residual)
  ln_out_k<<<dim3(SEQ), 256, 0, stream>>>(FNbf, LN1b, ln2_g, ln2_b, (float*)d_out);
}

// Round 23
// 260.189 us; speedup vs baseline: 1.1349x; 1.0096x over previous
//
#include <hip/hip_runtime.h>

// AutoDecoderLayer on MI355X.
// Algebra: with X=embdding, Y=history,
//   G = X^T X ; scoresT_h = (Wq_h G Wk_h^T + rank-1 bias)/32 (= scores^T)
//   AT_h = colsoftmax(scoresT_h) ; c_h = AT_h bv_h
//   M = sum_h Wv_h^T A_h Wz_h^T ;  d = bz + (Wz c)
//   O = Y M + d ; LN1 = LN(O)+X ; FN = LN1 Wf^T + bf ; out = LN(FN)+LN1
// R21: LN1 bf16-only (262.7us). R22: Gram split-K 8 -> 4 (288 GEMM blocks,
// K=1024 each; still > CU count so no R19-style tail; hidden under the
// conversion stream). Halves Gp write + plane_red read (-16MB total).

constexpr int EMB = 1024;
constexpr int SEQ = 4096;
constexpr int NH  = 8;

using f32x4  = __attribute__((ext_vector_type(4))) float;
using bf16x8 = __attribute__((ext_vector_type(8))) __bf16;
using us8    = __attribute__((ext_vector_type(8))) unsigned short;
using us4    = __attribute__((ext_vector_type(4))) unsigned short;

#define GLOAD_LDS16(g, l) __builtin_amdgcn_global_load_lds(                 \
    (const __attribute__((address_space(1))) void*)(g),                     \
    (__attribute__((address_space(3))) void*)(l), 16, 0, 0)

__device__ inline unsigned short f2bf(float x) {
  unsigned int u = __float_as_uint(x);
  u += 0x7FFFu + ((u >> 16) & 1u);   // round-to-nearest-even
  return (unsigned short)(u >> 16);
}
__device__ inline float bf2f(unsigned short h) {
  return __uint_as_float(((unsigned int)h) << 16);
}
__device__ inline f32x4 ntl4(const float* p) {
  return __builtin_nontemporal_load((const f32x4*)p);
}
__device__ inline us4 cvt4(f32x4 x) {
  us4 o; o[0] = f2bf(x[0]); o[1] = f2bf(x[1]); o[2] = f2bf(x[2]); o[3] = f2bf(x[3]);
  return o;
}

// ---------------------------------------------------------------- GEMM body
// C[m,n] = sum_k A[m*lda+k] * B[n*ldb+k], bf16 in, f32 acc.
// 64x128 tile, BK=64, 4 waves (2x2), single-buffered 24KB LDS, async
// global_load_lds staging. MODE 1: bf16 store. 2: bf16 store + transposed
// MIRROR store (symmetric Gram). 4: scoresT bf16 + col-softmax partials.
// 5: bf16 store + bias[n]. bx/by/z pre-decoded by caller.
template <int MODE>
__device__ __attribute__((always_inline)) void gemm_body(
    unsigned short* lds, int bx, int by, int z,
    const unsigned short* A, const unsigned short* B, void* Cout,
    int K, int lda, int ldb, int ldc,
    long long aZ, long long bZ, long long cZ,
    const float* e0, const float* e1, const float* e2, const float* e3,
    float* mpart, float* spart) {
  A += (size_t)z * aZ;
  B += (size_t)z * bZ;
  const int tid = threadIdx.x;
  const int lane = tid & 63, wid = tid >> 6;
  const int wm = wid >> 1, wn = wid & 1;     // 2x2 wave grid
  const int row0 = bx * 64, col0 = by * 128;

  unsigned short* As = lds;                  // [64][64]  8KB
  unsigned short* Bs = lds + 64 * 64;        // [128][64] 16KB

  f32x4 acc[2][4] = {};
  const int lrow = lane & 15, kg = lane >> 4;
  const int lr = lane >> 3;        // row within an 8-row chunk
  const int lc = (lane & 7) * 8;   // elem col within 64

  const int nt = K >> 6;
  for (int t = 0; t < nt; ++t) {
    const int k0 = t << 6;
#pragma unroll
    for (int c = 0; c < 2; ++c) {
      int chunk = wid * 2 + c;
      int r = chunk * 8 + lr;
      GLOAD_LDS16(A + (size_t)(row0 + r) * lda + k0 + lc, &As[chunk * 512]);
    }
#pragma unroll
    for (int c = 0; c < 4; ++c) {
      int chunk = wid * 4 + c;
      int r = chunk * 8 + lr;
      GLOAD_LDS16(B + (size_t)(col0 + r) * ldb + k0 + lc, &Bs[chunk * 512]);
    }
    __syncthreads();
#pragma unroll
    for (int ks = 0; ks < 2; ++ks) {
      bf16x8 a[2], b[4];
      int koff = ks * 32 + kg * 8;
#pragma unroll
      for (int i = 0; i < 2; ++i)
        a[i] = *(const bf16x8*)&As[(wm * 32 + i * 16 + lrow) * 64 + koff];
#pragma unroll
      for (int j = 0; j < 4; ++j)
        b[j] = *(const bf16x8*)&Bs[(wn * 64 + j * 16 + lrow) * 64 + koff];
#pragma unroll
      for (int i = 0; i < 2; ++i)
#pragma unroll
        for (int j = 0; j < 4; ++j)
          acc[i][j] = __builtin_amdgcn_mfma_f32_16x16x32_bf16(a[i], b[j], acc[i][j], 0, 0, 0);
    }
    __syncthreads();
  }

  const int rb = (lane >> 4) * 4, cc = lane & 15;
  unsigned short* Cs = lds;                // [64][128] 16KB
#pragma unroll
  for (int i = 0; i < 2; ++i) {
#pragma unroll
    for (int j = 0; j < 4; ++j) {
#pragma unroll
      for (int r = 0; r < 4; ++r) {
        float val = acc[i][j][r];
        int mm = wm * 32 + i * 16 + rb + r;
        int nn = wn * 64 + j * 16 + cc;
        if (MODE == 4) {
          int m = row0 + mm, n = col0 + nn;
          float bq = e0[z * EMB + m], uu = e1[z * EMB + n];
          float bk = e2[z * EMB + n], vv = e3[z * EMB + m];
          val = (val + bq * (uu + (float)SEQ * bk) + vv * bk) * (1.0f / 32.0f);
        } else if (MODE == 5) {
          val += e0[col0 + nn];
        }
        Cs[mm * 128 + nn] = f2bf(val);
      }
    }
  }
  __syncthreads();
  unsigned short* Cg = (unsigned short*)Cout + (size_t)z * cZ;
#pragma unroll
  for (int p = 0; p < 4; ++p) {
    int idx = p * 256 + tid;
    int row = idx >> 4, col = (idx & 15) * 8;
    *(us8*)(Cg + (size_t)(row0 + row) * ldc + col0 + col) =
        *(const us8*)&Cs[row * 128 + col];
  }
  if (MODE == 2) {
    // mirror store: G[col0+nn][row0+mm] = Cs[mm][nn] (identical values at
    // overlaps -> benign). 128 rows x 64 cols, us8 chunks (8 bf16).
#pragma unroll
    for (int p = 0; p < 4; ++p) {
      int idx = p * 256 + tid;               // 1024 chunks
      int rr = idx >> 3;                     // mirror row: nn in [0,128)
      int cg = (idx & 7) * 8;                // mirror col group: mm base
      us8 o;
#pragma unroll
      for (int e = 0; e < 8; ++e) o[e] = Cs[(cg + e) * 128 + rr];
      *(us8*)(Cg + (size_t)(col0 + rr) * ldc + row0 + cg) = o;
    }
  }
  if (MODE == 4) {
    // column softmax partials over this tile's 64 rows (2 threads/col),
    // computed from the SAME bf16 values at_cvec will read back.
    int colx = tid >> 1, half = tid & 1;
    float mx = -1e30f;
#pragma unroll 8
    for (int r = 0; r < 32; ++r)
      mx = fmaxf(mx, bf2f(Cs[(half * 32 + r) * 128 + colx]));
    mx = fmaxf(mx, __shfl_xor(mx, 1));
    float se = 0.f;
#pragma unroll 8
    for (int r = 0; r < 32; ++r)
      se += __expf(bf2f(Cs[(half * 32 + r) * 128 + colx]) - mx);
    se += __shfl_xor(se, 1);
    if (half == 0) {
      size_t soff = ((size_t)z * 16 + bx) * EMB + col0 + colx;
      mpart[soff] = mx;
      spart[soff] = se;
    }
  }
}

template <int MODE>
__global__ __launch_bounds__(256) void gemm_nt(const unsigned short* __restrict__ A,
                                               const unsigned short* __restrict__ B,
                                               void* __restrict__ Cout,
                                               int K, int lda, int ldb, int ldc,
                                               long long aZ, long long bZ, long long cZ,
                                               int nx, int ny,
                                               const float* __restrict__ e0,
                                               const float* __restrict__ e1,
                                               const float* __restrict__ e2,
                                               const float* __restrict__ e3,
                                               float* __restrict__ mpart,
                                               float* __restrict__ spart) {
  __shared__ __align__(16) unsigned short lds[(64 + 128) * 64];
  const int q = gridDim.x >> 3;                       // nwg % 8 == 0
  const int wg = (blockIdx.x & 7) * q + (blockIdx.x >> 3);
  const int bx = wg % nx, by = (wg / nx) % ny, z = wg / (nx * ny);
  gemm_body<MODE>(lds, bx, by, z, A, B, Cout, K, lda, ldb, ldc, aZ, bZ, cZ,
                  e0, e1, e2, e3, mpart, spart);
}

// ------------------- colsum_part + emb-transpose + Wv-transpose (one dispatch)
// [0,128): colsum partials; [128,1152): emb 64x64 tiles -> XT;
// [1152,3200): Wv 64x64 tiles -> WvT
__global__ __launch_bounds__(256) void colsum_xt_k(const float* __restrict__ emb,
                                                   const float* __restrict__ Wv,
                                                   float* __restrict__ part,
                                                   unsigned short* __restrict__ XT,
                                                   unsigned short* __restrict__ WvT) {
  __shared__ float tileT[64][65];
  const int b = blockIdx.x, tid = threadIdx.x;
  if (b < 128) {
    int e = (b & 3) * 256 + tid;
    int y = b >> 2;
    float s = 0.f;
    for (int r = y * 128; r < y * 128 + 128; ++r) s += emb[(size_t)r * EMB + e];
    part[y * EMB + e] = s;
    return;
  }
  const float* src; unsigned short* dst; int R, r0, c0;
  if (b < 1152) {
    int tb = b - 128;                      // emb [4096][1024] -> XT [1024][4096]
    src = emb; dst = XT; R = SEQ;
    r0 = (tb >> 4) * 64; c0 = (tb & 15) * 64;
  } else {
    int t2 = b - 1152, z = t2 >> 8, tt = t2 & 255;
    src = Wv + (size_t)z * EMB * EMB; dst = WvT + (size_t)z * EMB * EMB;
    R = EMB;
    r0 = (tt >> 4) * 64; c0 = (tt & 15) * 64;
  }
  int tx = tid & 15, ty = tid >> 4;        // 16 x 16 threads
#pragma unroll
  for (int p = 0; p < 4; ++p) {            // NT float4 loads, transposed scatter
    int ir = p * 16 + ty;
    f32x4 x = ntl4(src + (size_t)(r0 + ir) * EMB + c0 + tx * 4);
    tileT[tx * 4 + 0][ir] = x[0]; tileT[tx * 4 + 1][ir] = x[1];
    tileT[tx * 4 + 2][ir] = x[2]; tileT[tx * 4 + 3][ir] = x[3];
  }
  __syncthreads();
#pragma unroll
  for (int p = 0; p < 4; ++p) {            // contiguous LDS read, normal stores
    int orow = p * 16 + ty;
    f32x4 x;
    x[0] = tileT[orow][tx * 4 + 0]; x[1] = tileT[orow][tx * 4 + 1];
    x[2] = tileT[orow][tx * 4 + 2]; x[3] = tileT[orow][tx * 4 + 3];
    *(us4*)(dst + (size_t)(c0 + orow) * R + r0 + tx * 4) = cvt4(x);
  }
}

__global__ __launch_bounds__(256) void colsum_red_k(const float* __restrict__ part,
                                                    float* __restrict__ xbar) {
  int e = blockIdx.x * 256 + threadIdx.x;
  float s = 0.f;
  for (int y = 0; y < 32; ++y) s += part[y * EMB + e];
  xbar[e] = s;
}

// -------- FUSED: split-K(4) symmetric Gram GEMM (blocks [0,288)) + conversions
// Gram: 72 tiles (bx>=2by) x 4 z, K=1024 each, mirror-stored into Gp.
// GEMM blocks first so the (bx&7) swizzle aligns with round-robin XCDs.
// [288,4384)   Wk/Wq: one row per wave -> bf16 + dot(xbar) -> u/v
// [4384,6048)  flat conversions, 8192 f32/block: hist | Wz | Wf
__global__ __launch_bounds__(256) void gram_cvt_k(
    const unsigned short* __restrict__ XT, unsigned short* __restrict__ Gp,
    const float* __restrict__ Wk, const float* __restrict__ Wq,
    const float* __restrict__ hist, const float* __restrict__ Wz,
    const float* __restrict__ Wf, const float* __restrict__ xbar,
    unsigned short* __restrict__ Wkb, unsigned short* __restrict__ Wqb,
    unsigned short* __restrict__ Yb, unsigned short* __restrict__ Wzb,
    unsigned short* __restrict__ Wfb,
    float* __restrict__ u, float* __restrict__ v) {
  __shared__ __align__(16) unsigned short smem[(64 + 128) * 64];  // 24KB union
  const int tid = threadIdx.x;
  if (blockIdx.x < 288) {
    const int wg = ((int)blockIdx.x & 7) * 36 + ((int)blockIdx.x >> 3);
    const int t = wg % 72, z = wg / 72;           // z in [0,4)
    // decode t -> (bx,by): starts[by] = 16by - by(by-1)
    int by = 0, st = 0;
#pragma unroll
    for (int b = 7; b >= 1; --b) {
      int sb = 16 * b - b * (b - 1);
      if (t >= sb && by == 0) { by = b; st = sb; }
    }
    int bx = 2 * by + (t - st);
    gemm_body<2>(smem, bx, by, z, XT, XT, Gp, 1024, SEQ, SEQ, EMB,
                 1024, 1024, (long long)EMB * EMB,
                 nullptr, nullptr, nullptr, nullptr, nullptr, nullptr);
    return;
  }
  int c = blockIdx.x - 288;
  if (c < 4096) {                        // cvt + xbar-dot, one row per wave
    int gw = c * 4 + (tid >> 6);
    int lane = tid & 63;
    const float* src = (gw < 8192) ? Wk : Wq;
    unsigned short* dst = (gw < 8192) ? Wkb : Wqb;
    float* dot = (gw < 8192) ? u : v;
    int row = gw & 8191;
    const float* sr = src + (size_t)row * EMB;
    const float4* xb4 = (const float4*)xbar;
    unsigned short* dr = dst + (size_t)row * EMB;
    float s = 0.f;
#pragma unroll
    for (int j = 0; j < 4; ++j) {
      int idx = j * 64 + lane;
      f32x4 x = ntl4(sr + idx * 4);
      float4 xb = xb4[idx];
      *(us4*)(dr + idx * 4) = cvt4(x);
      s += x[0] * xb.x + x[1] * xb.y + x[2] * xb.z + x[3] * xb.w;
    }
#pragma unroll
    for (int off = 32; off; off >>= 1) s += __shfl_down(s, off);
    if (lane == 0) dot[row] = s;
  } else {                               // flat conversions, 8192 f32/block
    size_t f0 = (size_t)(c - 4096) * 8192;
    const float* src; unsigned short* dst; size_t loc;
    if (f0 < 4194304ull) { src = hist; dst = Yb; loc = f0; }
    else if (f0 < 12582912ull) { src = Wz; dst = Wzb; loc = f0 - 4194304ull; }
    else { src = Wf; dst = Wfb; loc = f0 - 12582912ull; }
#pragma unroll
    for (int p = 0; p < 8; ++p) {
      int i = p * 256 + tid;
      f32x4 x = ntl4(src + loc + i * 4);
      *(us4*)(dst + loc + i * 4) = cvt4(x);
    }
  }
}

// ------- FUSED: MpT GEMM (blocks [0,1024)) + dvec.  MpT_h = Wz_h * C_h^T
// (A = Wzb rows, lda=8192, head offset aZ=EMB in k; B = Cbf planes).
__global__ __launch_bounds__(256) void mp_dvec_k(
    const unsigned short* __restrict__ Cbf, const unsigned short* __restrict__ Wzb,
    unsigned short* __restrict__ MpT,
    const float* __restrict__ bz, const float* __restrict__ cvec,
    float* __restrict__ d) {
  __shared__ __align__(16) unsigned short smem[(64 + 128) * 64];
  const int tid = threadIdx.x;
  if (blockIdx.x < 1024) {
    const int wg = ((int)blockIdx.x & 7) * 128 + ((int)blockIdx.x >> 3);
    const int bx = wg % 16, by = (wg / 16) % 8, z = wg / 128;
    gemm_body<1>(smem, bx, by, z, Wzb, Cbf, MpT, EMB, NH * EMB, EMB, EMB,
                 (long long)EMB, (long long)EMB * EMB, (long long)EMB * EMB,
                 nullptr, nullptr, nullptr, nullptr, nullptr, nullptr);
    return;
  }
  // dvec: d[g] = bz[g] + dot(Wzb[g,:], cvec)
  int g = blockIdx.x - 1024;
  float* sb = (float*)smem;
  const unsigned short* row = Wzb + (size_t)g * (NH * EMB);
  float s = 0.f;
#pragma unroll
  for (int p = 0; p < 4; ++p) {
    int i = p * 256 + tid;
    us8 w = ((const us8*)row)[i];
    float4 c0 = ((const float4*)cvec)[i * 2];
    float4 c1 = ((const float4*)cvec)[i * 2 + 1];
    s += bf2f(w[0]) * c0.x + bf2f(w[1]) * c0.y + bf2f(w[2]) * c0.z + bf2f(w[3]) * c0.w;
    s += bf2f(w[4]) * c1.x + bf2f(w[5]) * c1.y + bf2f(w[6]) * c1.z + bf2f(w[7]) * c1.w;
  }
  int lane = tid & 63, w = tid >> 6;
#pragma unroll
  for (int off = 32; off; off >>= 1) s += __shfl_down(s, off);
  if (lane == 0) sb[w] = s;
  __syncthreads();
  if (tid == 0) d[g] = bz[g] + sb[0] + sb[1] + sb[2] + sb[3];
}

// out[i] = bf16( sum_z in[z][i] ), NZ bf16 planes (Gp NZ=4, MpT NZ=8)
template <int NZ>
__global__ __launch_bounds__(256) void plane_red_k(const unsigned short* __restrict__ in,
                                                   unsigned short* __restrict__ out) {
  int i = blockIdx.x * 256 + threadIdx.x;  // ushort4 index
  float4 s = {0.f, 0.f, 0.f, 0.f};
#pragma unroll
  for (int z = 0; z < NZ; ++z) {
    ushort4 v = ((const ushort4*)(in + (size_t)z * EMB * EMB))[i];
    s.x += bf2f(v.x); s.y += bf2f(v.y); s.z += bf2f(v.z); s.w += bf2f(v.w);
  }
  ushort4 o; o.x = f2bf(s.x); o.y = f2bf(s.y); o.z = f2bf(s.z); o.w = f2bf(s.w);
  ((ushort4*)out)[i] = o;
}

// ------------------------------------------- transposed-softmax pipeline
__global__ __launch_bounds__(256) void colstat2_k(const float* __restrict__ m_part,
                                                  const float* __restrict__ s_part,
                                                  float* __restrict__ mfin,
                                                  float* __restrict__ isfin) {
  int i = blockIdx.x * 256 + threadIdx.x;     // (h,col) flat, grid = 32
  int h = i >> 10, col = i & 1023;
  float M = -1e30f, S = 0.f;
#pragma unroll
  for (int c = 0; c < 16; ++c) {
    float m = m_part[((size_t)h * 16 + c) * EMB + col];
    float s = s_part[((size_t)h * 16 + c) * EMB + col];
    float nm = fmaxf(M, m);
    S = S * __expf(M - nm) + s * __expf(m - nm);
    M = nm;
  }
  mfin[i] = M;
  isfin[i] = 1.0f / S;
}

__global__ __launch_bounds__(256) void at_cvec_k(const unsigned short* __restrict__ ScT,
                                                 const float* __restrict__ mfin,
                                                 const float* __restrict__ isfin,
                                                 const float* __restrict__ bv,
                                                 unsigned short* __restrict__ AT,
                                                 float* __restrict__ cbuf) {
  __shared__ float sb[4];
  int f = blockIdx.x, h = blockIdx.y, tid = threadIdx.x;
  size_t rowoff = ((size_t)h * EMB + f) * EMB;
  ushort4 xr = ((const ushort4*)(ScT + rowoff))[tid];
  float4 m  = ((const float4*)(mfin + (size_t)h * EMB))[tid];
  float4 is = ((const float4*)(isfin + (size_t)h * EMB))[tid];
  float4 b  = ((const float4*)(bv + (size_t)h * EMB))[tid];
  float a0 = __expf(bf2f(xr.x) - m.x) * is.x;
  float a1 = __expf(bf2f(xr.y) - m.y) * is.y;
  float a2 = __expf(bf2f(xr.z) - m.z) * is.z;
  float a3 = __expf(bf2f(xr.w) - m.w) * is.w;
  ushort4 o; o.x = f2bf(a0); o.y = f2bf(a1); o.z = f2bf(a2); o.w = f2bf(a3);
  ((ushort4*)(AT + rowoff))[tid] = o;
  float s = a0 * b.x + a1 * b.y + a2 * b.z + a3 * b.w;
  int lane = tid & 63, w = tid >> 6;
#pragma unroll
  for (int off = 32; off; off >>= 1) s += __shfl_down(s, off);
  if (lane == 0) sb[w] = s;
  __syncthreads();
  if (tid == 0) cbuf[h * EMB + f] = sb[0] + sb[1] + sb[2] + sb[3];
}

// ---------------------------------------------------------------- LN
// mid-LN: Xin bf16, residual f32, OUTPUT bf16 ONLY (LN1 lives only in bf16).
__global__ __launch_bounds__(256) void ln_mid_k(const unsigned short* __restrict__ Xin,
                                                const float* __restrict__ resid,
                                                const float* __restrict__ gw,
                                                const float* __restrict__ bw,
                                                unsigned short* __restrict__ outb) {
  __shared__ float sb[16];
  int row = blockIdx.x, tid = threadIdx.x;
  ushort4 xr = ((const ushort4*)(Xin + (size_t)row * EMB))[tid];
  float v0 = bf2f(xr.x), v1 = bf2f(xr.y), v2 = bf2f(xr.z), v3 = bf2f(xr.w);
  float s = v0 + v1 + v2 + v3;
  float q = v0 * v0 + v1 * v1 + v2 * v2 + v3 * v3;
  int lane = tid & 63, w = tid >> 6;
#pragma unroll
  for (int off = 32; off; off >>= 1) { s += __shfl_down(s, off); q += __shfl_down(q, off); }
  if (lane == 0) { sb[w] = s; sb[8 + w] = q; }
  __syncthreads();
  float mu  = (sb[0] + sb[1] + sb[2] + sb[3]) * (1.0f / EMB);
  float var = (sb[8] + sb[9] + sb[10] + sb[11]) * (1.0f / EMB) - mu * mu;
  float rs = rsqrtf(var + 1e-5f);
  float4 rv = ((const float4*)(resid + (size_t)row * EMB))[tid];
  float4 gv = ((const float4*)gw)[tid];
  float4 bv = ((const float4*)bw)[tid];
  ushort4 ob;
  ob.x = f2bf((v0 - mu) * rs * gv.x + bv.x + rv.x);
  ob.y = f2bf((v1 - mu) * rs * gv.y + bv.y + rv.y);
  ob.z = f2bf((v2 - mu) * rs * gv.z + bv.z + rv.z);
  ob.w = f2bf((v3 - mu) * rs * gv.w + bv.w + rv.w);
  ((ushort4*)(outb + (size_t)row * EMB))[tid] = ob;
}

// final LN: Xin bf16, residual bf16, output f32 (d_out).
__global__ __launch_bounds__(256) void ln_out_k(const unsigned short* __restrict__ Xin,
                                                const unsigned short* __restrict__ resid,
                                                const float* __restrict__ gw,
                                                const float* __restrict__ bw,
                                                float* __restrict__ outf) {
  __shared__ float sb[16];
  int row = blockIdx.x, tid = threadIdx.x;
  ushort4 xr = ((const ushort4*)(Xin + (size_t)row * EMB))[tid];
  float v0 = bf2f(xr.x), v1 = bf2f(xr.y), v2 = bf2f(xr.z), v3 = bf2f(xr.w);
  float s = v0 + v1 + v2 + v3;
  float q = v0 * v0 + v1 * v1 + v2 * v2 + v3 * v3;
  int lane = tid & 63, w = tid >> 6;
#pragma unroll
  for (int off = 32; off; off >>= 1) { s += __shfl_down(s, off); q += __shfl_down(q, off); }
  if (lane == 0) { sb[w] = s; sb[8 + w] = q; }
  __syncthreads();
  float mu  = (sb[0] + sb[1] + sb[2] + sb[3]) * (1.0f / EMB);
  float var = (sb[8] + sb[9] + sb[10] + sb[11]) * (1.0f / EMB) - mu * mu;
  float rs = rsqrtf(var + 1e-5f);
  ushort4 rr = ((const ushort4*)(resid + (size_t)row * EMB))[tid];
  float4 gv = ((const float4*)gw)[tid];
  float4 bv = ((const float4*)bw)[tid];
  float4 ov;
  ov.x = (v0 - mu) * rs * gv.x + bv.x + bf2f(rr.x);
  ov.y = (v1 - mu) * rs * gv.y + bv.y + bf2f(rr.y);
  ov.z = (v2 - mu) * rs * gv.z + bv.z + bf2f(rr.z);
  ov.w = (v3 - mu) * rs * gv.w + bv.w + bf2f(rr.w);
  ((float4*)(outf + (size_t)row * EMB))[tid] = ov;
}

// ---------------------------------------------------------------- launch
extern "C" void kernel_launch(void* const* d_in, const int* in_sizes, int n_in,
                              void* d_out, int out_size, void* d_ws, size_t ws_size,
                              hipStream_t stream) {
  const float* history = (const float*)d_in[0];
  const float* emb     = (const float*)d_in[1];
  const float* Wq_w = (const float*)d_in[2];
  const float* Wq_b = (const float*)d_in[3];
  const float* Wk_w = (const float*)d_in[4];
  const float* Wk_b = (const float*)d_in[5];
  const float* Wv_w = (const float*)d_in[6];
  const float* Wv_b = (const float*)d_in[7];
  const float* Wz_w = (const float*)d_in[8];
  const float* Wz_b = (const float*)d_in[9];
  const float* ln1_g = (const float*)d_in[10];
  const float* ln1_b = (const float*)d_in[11];
  const float* Wf_w = (const float*)d_in[12];
  const float* Wf_b = (const float*)d_in[13];
  const float* ln2_g = (const float*)d_in[14];
  const float* ln2_b = (const float*)d_in[15];

  char* ws = (char*)d_ws;
  const size_t MB = 1024ull * 1024ull;
  unsigned short* XT  = (unsigned short*)(ws + 0);        // [E][S] bf16, 8MB ; later LN1b
  unsigned short* Ybf = (unsigned short*)(ws + 8 * MB);   // [S][E] bf16, 8MB
  unsigned short* Wkb = (unsigned short*)(ws + 16 * MB);  // [H][E][E] bf16, 16MB
  unsigned short* Wqb = (unsigned short*)(ws + 32 * MB);
  unsigned short* WvT = (unsigned short*)(ws + 48 * MB);  // [H][E'][E] transposed
  unsigned short* Wzb = (unsigned short*)(ws + 64 * MB);  // [E][H*E]
  unsigned short* Wfb = (unsigned short*)(ws + 80 * MB);  // [E][E], 2MB
  unsigned short* Gbf = (unsigned short*)(ws + 82 * MB);  // [E][E] bf16 (symmetric), 2MB
  float* xpart = (float*)(ws + 84 * MB);                  // 128 KB
  float* xbar  = (float*)(ws + 84 * MB + 160 * 1024);     // 4 KB
  float* ubuf  = (float*)(ws + 84 * MB + 192 * 1024);     // [H][E] 32 KB
  float* vbuf  = (float*)(ws + 84 * MB + 256 * 1024);
  float* cbuf  = (float*)(ws + 84 * MB + 320 * 1024);     // [H][E]
  float* dbuf  = (float*)(ws + 84 * MB + 384 * 1024);     // [E]
  unsigned short* Tbf = (unsigned short*)(ws + 85 * MB);  // 16MB; later Cbf, later FNbf
  float* Sc  = (float*)(ws + 101 * MB);                   // 32MB region: Gp/ScT/MpT (bf16)
  char*  St  = ws + 133 * MB;                             // stats; later Obf
  unsigned short* ATb = (unsigned short*)(ws + 149 * MB); // 16MB
  unsigned short* MTb = (unsigned short*)(ws + 165 * MB); // 2MB
  float* m_part = (float*)(St);                  // 512 KB [H][16][E]
  float* s_part = (float*)(St + 512 * 1024);     // 512 KB
  float* mfin   = (float*)(St + 1024 * 1024);    // 32 KB [H][E]
  float* isfin  = (float*)(St + 1056 * 1024);    // 32 KB
  // aliases (lifetimes verified non-overlapping)
  unsigned short* Gp  = (unsigned short*)Sc;  // [4][E][E] bf16 Gram partials
  unsigned short* ScT = (unsigned short*)Sc;  // [H][E][E] bf16 scoresT (after Gp)
  unsigned short* Cbf = Tbf;
  unsigned short* MpT = (unsigned short*)Sc;  // [H][E][E] bf16 (after ScT consumed)
  unsigned short* Obf = (unsigned short*)St;  // [S][E] bf16 (after stats consumed)
  unsigned short* LN1b = XT;                  // [S][E] bf16 (XT dead after Gram)
  unsigned short* FNbf = Tbf;                 // [S][E] bf16 (after Cbf consumed)
  const long long EE = (long long)EMB * EMB;

  // --- colsum partials + emb/Wv transposes (one dispatch), then xbar
  colsum_xt_k<<<dim3(3200), 256, 0, stream>>>(emb, Wv_w, xpart, XT, WvT);
  colsum_red_k<<<dim3(4), 256, 0, stream>>>(xpart, xbar);

  // --- FUSED: split-K(4) symmetric Gram + remaining conversions
  gram_cvt_k<<<dim3(6048), 256, 0, stream>>>(XT, Gp,
                                             Wk_w, Wq_w, history, Wz_w, Wf_w,
                                             xbar,
                                             Wkb, Wqb, Ybf, Wzb, Wfb,
                                             ubuf, vbuf);
  plane_red_k<4><<<dim3(EMB * EMB / 4 / 256), 256, 0, stream>>>(Gp, Gbf);
  // --- T2_h = Wq_h * G  (G symmetric; NT B-operand)
  gemm_nt<1><<<dim3(1024), 256, 0, stream>>>(Wqb, Gbf, Tbf, EMB, EMB, EMB, EMB,
                                             EE, 0, EE, 16, 8,
                                             nullptr, nullptr, nullptr, nullptr,
                                             nullptr, nullptr);
  // --- scoresT_h = (T2_h * Wk_h^T + rank-1)/32 -> bf16 + col-stat partials
  gemm_nt<4><<<dim3(1024), 256, 0, stream>>>(Tbf, Wkb, ScT, EMB, EMB, EMB, EMB,
                                             EE, EE, EE, 16, 8,
                                             Wq_b, ubuf, Wk_b, vbuf,
                                             m_part, s_part);
  // --- merge column softmax stats (32 blocks, done once)
  colstat2_k<<<dim3(32), 256, 0, stream>>>(m_part, s_part, mfin, isfin);
  // --- AT = exp(scoresT - m)*is (bf16) fused with cvec dot
  at_cvec_k<<<dim3(EMB, NH), 256, 0, stream>>>(ScT, mfin, isfin, Wv_b, ATb, cbuf);
  // --- C_h = WvT_h * AT_h^T  == Wv_h^T A_h
  gemm_nt<1><<<dim3(1024), 256, 0, stream>>>(WvT, ATb, Cbf, EMB, EMB, EMB, EMB,
                                             EE, EE, EE, 16, 8,
                                             nullptr, nullptr, nullptr, nullptr,
                                             nullptr, nullptr);
  // --- FUSED: MpT_h = Wz_h * C_h^T + dvec
  mp_dvec_k<<<dim3(2048), 256, 0, stream>>>(Cbf, Wzb, MpT, Wz_b, cbuf, dbuf);
  // --- MT = sum_h MpT_h (plain 8-plane reduction, no transpose)
  plane_red_k<8><<<dim3(EMB * EMB / 4 / 256), 256, 0, stream>>>(MpT, MTb);
  // --- O = Y * M + d  (bf16 out; stats region consumed already)
  gemm_nt<5><<<dim3(512), 256, 0, stream>>>(Ybf, MTb, Obf, EMB, EMB, EMB, EMB,
                                            0, 0, 0, 64, 8,
                                            dbuf, nullptr, nullptr, nullptr,
                                            nullptr, nullptr);
  // --- LN1 = LN(O)+emb  (bf16 ONLY)
  ln_mid_k<<<dim3(SEQ), 256, 0, stream>>>(Obf, emb, ln1_g, ln1_b, LN1b);
  // --- FN = LN1 * Wf^T + bf  (bf16 out, overwrites Cbf region)
  gemm_nt<5><<<dim3(512), 256, 0, stream>>>(LN1b, Wfb, FNbf, EMB, EMB, EMB, EMB,
                                            0, 0, 0, 64, 8,
                                            Wf_b, nullptr, nullptr, nullptr,
                                            nullptr, nullptr);
  // --- out = LN(FN)+LN1  (bf16 residual)
  ln_out_k<<<dim3(SEQ), 256, 0, stream>>>(FNbf, LN1b, ln2_g, ln2_b, (float*)d_out);
}